// Round 1
// baseline (7124.042 us; speedup 1.0000x reference)
//
#include <hip/hip_runtime.h>
#include <math.h>

// FineGrainedRetriever: 2-layer SAGE + edge MLP scorer, fp32 baseline.
// Key algebra: segment_mean(x[src]+h_r) = (xscatter(x) + hsum)/cnt with hsum,cnt
// layer-invariant; q-part of pred GEMM precomputed (K 1536->1280).

namespace {
constexpr int E    = 200000;
constexpr int NV   = 50000;
constexpr int D    = 256;
constexpr int TWOE = 2 * E;
constexpr int BM   = 32;   // rows per GEMM block
constexpr int KC   = 8;    // K chunk
constexpr int ASTR = 36;   // padded stride of a_lds [KC][ASTR] (16B-aligned groups)
constexpr int HS   = 260;  // padded stride of hid  [BM][HS]
}

// ---- edge_index dtype probe (int64 vs int32) -------------------------------
__global__ void k_detect(const void* ei_raw, int* flag) {
  __shared__ int bad;
  if (threadIdx.x == 0) bad = 0;
  __syncthreads();
  const long long* p = (const long long*)ei_raw;
  long long v = p[threadIdx.x];  // 256 probes, in-bounds for both layouts
  if (v < 0 || v >= (long long)NV) atomicOr(&bad, 1);
  __syncthreads();
  if (threadIdx.x == 0) *flag = bad ? 0 : 1;  // 1 => data is int64
}

__global__ void k_convert(const void* ei_raw, const int* __restrict__ flag,
                          int* __restrict__ ei32) {
  int i = blockIdx.x * 256 + threadIdx.x;
  if (i >= TWOE) return;
  if (*flag) ei32[i] = (int)((const long long*)ei_raw)[i];
  else       ei32[i] = ((const int*)ei_raw)[i];
}

// ---- forward-edge scatter: hsum[t] += edge_attr[e]; counts both directions --
__global__ void k_fwd_scatter(const float* __restrict__ ea, const int* __restrict__ ei32,
                              float* __restrict__ hsum, float* __restrict__ cnt) {
  int e = blockIdx.x * 4 + (threadIdx.x >> 6);  // grid = E/4 exact
  int l = threadIdx.x & 63;
  int t = ei32[E + e];
  float4 v = *(const float4*)(ea + (size_t)e * D + l * 4);
  float* dst = hsum + (size_t)t * D + l * 4;
  atomicAdd(dst + 0, v.x); atomicAdd(dst + 1, v.y);
  atomicAdd(dst + 2, v.z); atomicAdd(dst + 3, v.w);
  if (l == 0) atomicAdd(cnt + t, 1.0f);
  if (l == 1) atomicAdd(cnt + ei32[e], 1.0f);
}

// ---- GEMM inner micro-kernel (4x8 per thread) ------------------------------
#define GEMM_INNER(ACC, ALDS, WLDS)                                   \
  _Pragma("unroll")                                                   \
  for (int kk = 0; kk < KC; kk++) {                                   \
    float4 av = *(float4*)&ALDS[kk * ASTR + 4 * rg];                  \
    float4 w0 = *(float4*)&WLDS[kk * D + 8 * cg];                     \
    float4 w1 = *(float4*)&WLDS[kk * D + 8 * cg + 4];                 \
    float aa[4] = {av.x, av.y, av.z, av.w};                           \
    float ww[8] = {w0.x, w0.y, w0.z, w0.w, w1.x, w1.y, w1.z, w1.w};   \
    _Pragma("unroll") for (int r = 0; r < 4; r++)                     \
      _Pragma("unroll") for (int c = 0; c < 8; c++)                   \
        ACC[r][c] += aa[r] * ww[c];                                   \
  }

// ---- proj MLP over edges, fused scatter of ea_rev into hsum[h] -------------
__global__ __launch_bounds__(256) void k_proj_scatter(
    const float* __restrict__ ea,
    const float* __restrict__ W1, const float* __restrict__ b1,
    const float* __restrict__ W2, const float* __restrict__ b2,
    const int* __restrict__ ei32, float* __restrict__ hsum) {
  __shared__ float a_lds[KC * ASTR];
  __shared__ float w_lds[KC * D];
  __shared__ float hid[BM * HS];
  __shared__ int eh[BM];
  int tid = threadIdx.x;
  int e0 = blockIdx.x * BM;
  if (tid < BM) eh[tid] = ei32[e0 + tid];
  int rg = tid >> 5, cg = tid & 31;
  int lm = tid >> 3, lk = tid & 7;
  float acc[4][8];
#pragma unroll
  for (int r = 0; r < 4; r++)
#pragma unroll
    for (int c = 0; c < 8; c++) acc[r][c] = 0.f;

  // GEMM1: hid = relu(ea_tile @ W1 + b1)
  for (int k0 = 0; k0 < D; k0 += KC) {
    __syncthreads();
    a_lds[lk * ASTR + lm] = ea[(size_t)(e0 + lm) * D + k0 + lk];
    int wc = cg * 8;
    *(float4*)&w_lds[rg * D + wc]     = *(const float4*)&W1[(size_t)(k0 + rg) * D + wc];
    *(float4*)&w_lds[rg * D + wc + 4] = *(const float4*)&W1[(size_t)(k0 + rg) * D + wc + 4];
    __syncthreads();
    GEMM_INNER(acc, a_lds, w_lds)
  }
  __syncthreads();
#pragma unroll
  for (int r = 0; r < 4; r++) {
    int row = 4 * rg + r;
#pragma unroll
    for (int c = 0; c < 8; c++) {
      int col = 8 * cg + c;
      float v = acc[r][c] + b1[col];
      hid[row * HS + col] = v > 0.f ? v : 0.f;
      acc[r][c] = 0.f;
    }
  }
  // GEMM2: out = hid @ W2 + b2 (A read broadcast-style from hid)
  for (int k0 = 0; k0 < D; k0 += KC) {
    __syncthreads();
    {
      int wc = cg * 8;
      *(float4*)&w_lds[rg * D + wc]     = *(const float4*)&W2[(size_t)(k0 + rg) * D + wc];
      *(float4*)&w_lds[rg * D + wc + 4] = *(const float4*)&W2[(size_t)(k0 + rg) * D + wc + 4];
    }
    __syncthreads();
#pragma unroll
    for (int kk = 0; kk < KC; kk++) {
      float aa[4];
#pragma unroll
      for (int r = 0; r < 4; r++) aa[r] = hid[(4 * rg + r) * HS + k0 + kk];
      float4 w0 = *(float4*)&w_lds[kk * D + 8 * cg];
      float4 w1 = *(float4*)&w_lds[kk * D + 8 * cg + 4];
      float ww[8] = {w0.x, w0.y, w0.z, w0.w, w1.x, w1.y, w1.z, w1.w};
#pragma unroll
      for (int r = 0; r < 4; r++)
#pragma unroll
        for (int c = 0; c < 8; c++) acc[r][c] += aa[r] * ww[c];
    }
  }
  // scatter ea_rev rows into hsum[h_id[e]]
#pragma unroll
  for (int r = 0; r < 4; r++) {
    int row = 4 * rg + r;
    float* dst = hsum + (size_t)eh[row] * D + 8 * cg;
#pragma unroll
    for (int c = 0; c < 8; c++) atomicAdd(dst + c, acc[r][c] + b2[8 * cg + c]);
  }
}

// ---- per-layer scatter: xsum[dst] += x[src] over 2E directed edges ---------
__global__ void k_xscatter(const float* __restrict__ x, const int* __restrict__ ei32,
                           float* __restrict__ xsum) {
  int de = blockIdx.x * 4 + (threadIdx.x >> 6);  // grid = TWOE/4 exact
  int l = threadIdx.x & 63;
  int s = ei32[de];  // src == ei32[de] for both halves
  int dn = (de < E) ? ei32[de + E] : ei32[de - E];
  float4 v = *(const float4*)(x + (size_t)s * D + l * 4);
  float* dst = xsum + (size_t)dn * D + l * 4;
  atomicAdd(dst + 0, v.x); atomicAdd(dst + 1, v.y);
  atomicAdd(dst + 2, v.z); atomicAdd(dst + 3, v.w);
}

// ---- SAGE linear: out = relu([x | (xsum+hsum)/max(cnt,1)] @ W + b) ---------
__global__ __launch_bounds__(256) void k_sage(
    const float* __restrict__ x, const float* __restrict__ xsum,
    const float* __restrict__ hsum, const float* __restrict__ cnt,
    const float* __restrict__ W, const float* __restrict__ b,
    float* __restrict__ out) {
  __shared__ float a_lds[KC * ASTR];
  __shared__ float w_lds[KC * D];
  __shared__ float rinv[BM];
  int tid = threadIdx.x;
  int n0 = blockIdx.x * BM;
  if (tid < BM) {
    int n = n0 + tid;
    float c = (n < NV) ? cnt[n] : 1.f;
    rinv[tid] = 1.f / fmaxf(c, 1.f);
  }
  int rg = tid >> 5, cg = tid & 31;
  int lm = tid >> 3, lk = tid & 7;
  float acc[4][8];
#pragma unroll
  for (int r = 0; r < 4; r++)
#pragma unroll
    for (int c = 0; c < 8; c++) acc[r][c] = 0.f;

  for (int k0 = 0; k0 < 2 * D; k0 += KC) {
    __syncthreads();
    {
      int n = n0 + lm, k = k0 + lk;
      float av = 0.f;
      if (n < NV) {
        if (k < D) av = x[(size_t)n * D + k];
        else {
          int i = k - D;
          av = (xsum[(size_t)n * D + i] + hsum[(size_t)n * D + i]) * rinv[lm];
        }
      }
      a_lds[lk * ASTR + lm] = av;
      int wc = cg * 8;
      *(float4*)&w_lds[rg * D + wc]     = *(const float4*)&W[(size_t)(k0 + rg) * D + wc];
      *(float4*)&w_lds[rg * D + wc + 4] = *(const float4*)&W[(size_t)(k0 + rg) * D + wc + 4];
    }
    __syncthreads();
    GEMM_INNER(acc, a_lds, w_lds)
  }
#pragma unroll
  for (int r = 0; r < 4; r++) {
    int n = n0 + 4 * rg + r;
    if (n < NV) {
#pragma unroll
      for (int c = 0; c < 8; c++) {
        float v = acc[r][c] + b[8 * cg + c];
        out[(size_t)n * D + 8 * cg + c] = v > 0.f ? v : 0.f;
      }
    }
  }
}

// ---- qW[n] = q @ pred_W1[:256,n] + pred_b1[n] ------------------------------
__global__ void k_qw(const float* __restrict__ q, const float* __restrict__ W1,
                     const float* __restrict__ b1, float* __restrict__ qW) {
  __shared__ float ql[D];
  int n = threadIdx.x;
  ql[n] = q[n];
  __syncthreads();
  float s = b1[n];
  for (int k = 0; k < D; k++) s += ql[k] * W1[(size_t)k * D + n];
  qW[n] = s;
}

// ---- pred MLP over edges (K=1280 after q-fold), fused W2 dot + sampling ----
__global__ __launch_bounds__(256) void k_pred(
    const float* __restrict__ out0, const float* __restrict__ out1,
    const float* __restrict__ ea, const float* __restrict__ pW1,
    const float* __restrict__ qW, const float* __restrict__ pW2,
    const float* __restrict__ pb2, const float* __restrict__ noise,
    const int* __restrict__ ei32, float* __restrict__ dout) {
  __shared__ float a_lds[KC * ASTR];
  __shared__ float w_lds[KC * D];
  __shared__ int eh[BM], et[BM];
  int tid = threadIdx.x;
  int e0 = blockIdx.x * BM;
  if (tid < BM) { eh[tid] = ei32[e0 + tid]; et[tid] = ei32[E + e0 + tid]; }
  int rg = tid >> 5, cg = tid & 31;
  int lm = tid >> 3, lk = tid & 7;
  float acc[4][8];
#pragma unroll
  for (int r = 0; r < 4; r++)
#pragma unroll
    for (int c = 0; c < 8; c++) acc[r][c] = 0.f;

  for (int k0 = 0; k0 < 1280; k0 += KC) {
    __syncthreads();
    {
      int k = k0 + lk;
      float av;
      if (k < 256)       av = out0[(size_t)eh[lm] * D + k];
      else if (k < 512)  av = out1[(size_t)eh[lm] * D + (k - 256)];
      else if (k < 768)  av = ea[(size_t)(e0 + lm) * D + (k - 512)];
      else if (k < 1024) av = out0[(size_t)et[lm] * D + (k - 768)];
      else               av = out1[(size_t)et[lm] * D + (k - 1024)];
      a_lds[lk * ASTR + lm] = av;
      int wc = cg * 8;
      *(float4*)&w_lds[rg * D + wc]     = *(const float4*)&pW1[(size_t)(256 + k0 + rg) * D + wc];
      *(float4*)&w_lds[rg * D + wc + 4] = *(const float4*)&pW1[(size_t)(256 + k0 + rg) * D + wc + 4];
    }
    __syncthreads();
    GEMM_INNER(acc, a_lds, w_lds)
  }
  // epilogue: relu(hidden) . pred_W2, half-wave reduce, sample
  float w2[8];
#pragma unroll
  for (int c = 0; c < 8; c++) w2[c] = pW2[8 * cg + c];
  float p[4];
#pragma unroll
  for (int r = 0; r < 4; r++) {
    float s = 0.f;
#pragma unroll
    for (int c = 0; c < 8; c++) {
      float h = acc[r][c] + qW[8 * cg + c];
      h = h > 0.f ? h : 0.f;
      s += h * w2[c];
    }
    p[r] = s;
  }
#pragma unroll
  for (int m = 16; m >= 1; m >>= 1) {
#pragma unroll
    for (int r = 0; r < 4; r++) p[r] += __shfl_xor(p[r], m);
  }
  if (cg == 0) {
    float b2v = pb2[0];
#pragma unroll
    for (int r = 0; r < 4; r++) {
      int e = e0 + 4 * rg + r;
      float lg = p[r] + b2v;
      float nz = noise[e];
      float rn = logf(nz) - logf(1.f - nz);
      dout[e] = lg;
      dout[E + e] = 1.f / (1.f + expf(-(lg + rn)));
    }
  }
}

extern "C" void kernel_launch(void* const* d_in, const int* in_sizes, int n_in,
                              void* d_out, int out_size, void* d_ws, size_t ws_size,
                              hipStream_t stream) {
  const float* entity = (const float*)d_in[0];
  const float* ea     = (const float*)d_in[1];
  const float* q      = (const float*)d_in[2];
  const float* noise  = (const float*)d_in[3];
  const float* W_pr1  = (const float*)d_in[4];
  const float* b_pr1  = (const float*)d_in[5];
  const float* W_pr2  = (const float*)d_in[6];
  const float* b_pr2  = (const float*)d_in[7];
  const float* sW0    = (const float*)d_in[8];
  const float* sb0    = (const float*)d_in[9];
  const float* sW1    = (const float*)d_in[10];
  const float* sb1    = (const float*)d_in[11];
  const float* pW1    = (const float*)d_in[12];
  const float* pb1    = (const float*)d_in[13];
  const float* pW2    = (const float*)d_in[14];
  const float* pb2    = (const float*)d_in[15];
  const void*  ei_raw = d_in[16];

  char* ws = (char*)d_ws;
  size_t off = 0;
  const size_t NDB = (size_t)NV * D * 4;
  float* hsum = (float*)(ws + off); off += NDB;
  float* xsum = (float*)(ws + off); off += NDB;
  float* out0 = (float*)(ws + off); off += NDB;
  float* out1 = (float*)(ws + off); off += NDB;
  float* cnt  = (float*)(ws + off); off += (size_t)NV * 4;
  float* qW   = (float*)(ws + off); off += 1024;
  int*   ei32 = (int*)(ws + off);   off += (size_t)TWOE * 4;
  int*   flag = (int*)(ws + off);   off += 16;

  hipMemsetAsync(hsum, 0, NDB, stream);
  hipMemsetAsync(cnt, 0, (size_t)NV * 4, stream);
  k_detect<<<1, 256, 0, stream>>>(ei_raw, flag);
  k_convert<<<(TWOE + 255) / 256, 256, 0, stream>>>(ei_raw, flag, ei32);
  k_fwd_scatter<<<E / 4, 256, 0, stream>>>(ea, ei32, hsum, cnt);
  k_proj_scatter<<<E / BM, 256, 0, stream>>>(ea, W_pr1, b_pr1, W_pr2, b_pr2, ei32, hsum);

  // layer 0
  hipMemsetAsync(xsum, 0, NDB, stream);
  k_xscatter<<<TWOE / 4, 256, 0, stream>>>(entity, ei32, xsum);
  k_sage<<<(NV + BM - 1) / BM, 256, 0, stream>>>(entity, xsum, hsum, cnt, sW0, sb0, out0);
  // layer 1
  hipMemsetAsync(xsum, 0, NDB, stream);
  k_xscatter<<<TWOE / 4, 256, 0, stream>>>(out0, ei32, xsum);
  k_sage<<<(NV + BM - 1) / BM, 256, 0, stream>>>(out0, xsum, hsum, cnt, sW1, sb1, out1);

  k_qw<<<1, 256, 0, stream>>>(q, pW1, pb1, qW);
  k_pred<<<E / BM, 256, 0, stream>>>(out0, out1, ea, pW1, qW, pW2, pb2, noise, ei32,
                                     (float*)d_out);
}

// Round 2
// 4294.933 us; speedup vs baseline: 1.6587x; 1.6587x over previous
//
#include <hip/hip_runtime.h>
#include <math.h>

// FineGrainedRetriever round 2: MFMA split-bf16 GEMMs + pred-GEMM algebraic collapse.
// hidden[e] = qW + HEh[h_e] + EA2[e] + HEt[t_e]; all GEMMs 32x32x16 bf16 MFMA with
// fp32 accuracy via hi/lo split (3 mfma per tile). Scatters unchanged (atomics).

namespace {
constexpr int E    = 200000;
constexpr int NV   = 50000;
constexpr int D    = 256;
constexpr int TWOE = 2 * E;
}

typedef __attribute__((ext_vector_type(8))) short bf16x8;
typedef __attribute__((ext_vector_type(16))) float f32x16;

#define MFMA(a, b, c) __builtin_amdgcn_mfma_f32_32x32x16_bf16((a), (b), (c), 0, 0, 0)

__device__ inline void split2(float x, short& h, short& lo) {
  unsigned u = __float_as_uint(x);
  unsigned hb = u & 0xffff0000u;
  h = (short)(hb >> 16);
  float r = x - __uint_as_float(hb);   // exact
  lo = (short)(__float_as_uint(r) >> 16);
}

// ---- edge_index dtype probe (int64 vs int32) -------------------------------
__global__ void k_detect(const void* ei_raw, int* flag) {
  __shared__ int bad;
  if (threadIdx.x == 0) bad = 0;
  __syncthreads();
  const long long* p = (const long long*)ei_raw;
  long long v = p[threadIdx.x];
  if (v < 0 || v >= (long long)NV) atomicOr(&bad, 1);
  __syncthreads();
  if (threadIdx.x == 0) *flag = bad ? 0 : 1;  // 1 => int64
}

__global__ void k_convert(const void* ei_raw, const int* __restrict__ flag,
                          int* __restrict__ ei32) {
  int i = blockIdx.x * 256 + threadIdx.x;
  if (i >= TWOE) return;
  if (*flag) ei32[i] = (int)((const long long*)ei_raw)[i];
  else       ei32[i] = ((const int*)ei_raw)[i];
}

// ---- forward-edge scatter: hsum[t] += ea[e]; counts both directions --------
__global__ void k_fwd_scatter(const float* __restrict__ ea, const int* __restrict__ ei32,
                              float* __restrict__ hsum, float* __restrict__ cnt) {
  int e = blockIdx.x * 4 + (threadIdx.x >> 6);
  int l = threadIdx.x & 63;
  int t = ei32[E + e];
  float4 v = *(const float4*)(ea + (size_t)e * D + l * 4);
  float* dst = hsum + (size_t)t * D + l * 4;
  atomicAdd(dst + 0, v.x); atomicAdd(dst + 1, v.y);
  atomicAdd(dst + 2, v.z); atomicAdd(dst + 3, v.w);
  if (l == 0) atomicAdd(cnt + t, 1.0f);
  if (l == 1) atomicAdd(cnt + ei32[e], 1.0f);
}

// ---- per-layer scatter: xsum[dst] += x[src] over 2E directed edges ---------
__global__ void k_xscatter(const float* __restrict__ x, const int* __restrict__ ei32,
                           float* __restrict__ xsum) {
  int de = blockIdx.x * 4 + (threadIdx.x >> 6);
  int l = threadIdx.x & 63;
  int s = ei32[de];
  int dn = (de < E) ? ei32[de + E] : ei32[de - E];
  float4 v = *(const float4*)(x + (size_t)s * D + l * 4);
  float* dst = xsum + (size_t)dn * D + l * 4;
  atomicAdd(dst + 0, v.x); atomicAdd(dst + 1, v.y);
  atomicAdd(dst + 2, v.z); atomicAdd(dst + 3, v.w);
}

__global__ void k_rinv(const float* __restrict__ cnt, float* __restrict__ rinv) {
  int n = blockIdx.x * 256 + threadIdx.x;
  if (n < NV) rinv[n] = 1.f / fmaxf(cnt[n], 1.f);
}

// ---- weight prep: W[K][256] f32 -> Wf_hi/Wf_lo [K/8][256][8] bf16 ----------
__global__ __launch_bounds__(256) void k_wprep(const float* __restrict__ W,
                                               short* __restrict__ Wh,
                                               short* __restrict__ Wl) {
  __shared__ float tl[32][260];
  int tid = threadIdx.x;
  int k0 = blockIdx.x * 32;
#pragma unroll
  for (int i = 0; i < 32; i++) tl[i][tid] = W[(size_t)(k0 + i) * 256 + tid];
  __syncthreads();
  bf16x8* WhV = (bf16x8*)Wh;
  bf16x8* WlV = (bf16x8*)Wl;
#pragma unroll
  for (int kg = 0; kg < 4; kg++) {
    bf16x8 ph, pl;
#pragma unroll
    for (int j = 0; j < 8; j++) {
      short h, lo;
      split2(tl[kg * 8 + j][tid], h, lo);
      ph[j] = h; pl[j] = lo;
    }
    WhV[(size_t)((k0 >> 3) + kg) * 256 + tid] = ph;
    WlV[(size_t)((k0 >> 3) + kg) * 256 + tid] = pl;
  }
}

// ---- qW[n] = q @ pred_W1[:256,n] + pred_b1[n] ------------------------------
__global__ void k_qw(const float* __restrict__ q, const float* __restrict__ W1,
                     const float* __restrict__ b1, float* __restrict__ qW) {
  __shared__ float ql[D];
  int n = threadIdx.x;
  ql[n] = q[n];
  __syncthreads();
  float s = b1[n];
  for (int k = 0; k < D; k++) s += ql[k] * W1[(size_t)k * D + n];
  qW[n] = s;
}

// ---- generic MFMA GEMM: out = epi(A[M x K] @ Wf + ...) , N=256 -------------
enum AM { A_SINGLE, A_DUAL, A_DUAL_AGG };
enum EP { EP_RELU_BIAS, EP_PLAIN, EP_BIAS_SCATTER, EP_EDGE };

template<int AMODE>
__device__ inline void loadA8(const float* __restrict__ A0, const float* __restrict__ A1,
                              const float* __restrict__ hs, const float* __restrict__ rv,
                              int M, int row, int k, float* v) {
  if (row >= M) {
#pragma unroll
    for (int j = 0; j < 8; j++) v[j] = 0.f;
    return;
  }
  if (AMODE == A_SINGLE || k < 256) {
    const float4* p = (const float4*)(A0 + (size_t)row * 256 + k);
    float4 a = p[0], b = p[1];
    v[0] = a.x; v[1] = a.y; v[2] = a.z; v[3] = a.w;
    v[4] = b.x; v[5] = b.y; v[6] = b.z; v[7] = b.w;
  } else {
    size_t i = (size_t)row * 256 + (k - 256);
    const float4* p1 = (const float4*)(A1 + i);
    float4 a = p1[0], b = p1[1];
    if (AMODE == A_DUAL) {
      v[0] = a.x; v[1] = a.y; v[2] = a.z; v[3] = a.w;
      v[4] = b.x; v[5] = b.y; v[6] = b.z; v[7] = b.w;
    } else {
      const float4* p2 = (const float4*)(hs + i);
      float4 c = p2[0], d = p2[1];
      float r = rv[row];
      v[0] = (a.x + c.x) * r; v[1] = (a.y + c.y) * r;
      v[2] = (a.z + c.z) * r; v[3] = (a.w + c.w) * r;
      v[4] = (b.x + d.x) * r; v[5] = (b.y + d.y) * r;
      v[6] = (b.z + d.z) * r; v[7] = (b.w + d.w) * r;
    }
  }
}

template<int AMODE, int EPI>
__global__ __launch_bounds__(256) void k_gemm(
    const float* __restrict__ A0, const float* __restrict__ A1,
    const float* __restrict__ hs, const float* __restrict__ rv,
    const short* __restrict__ Wh, const short* __restrict__ Wl,
    const float* __restrict__ bias, float* __restrict__ out,
    const int* __restrict__ eidx, float* __restrict__ scat,
    const float* __restrict__ HEh, const float* __restrict__ HEt,
    const float* __restrict__ qW, const float* __restrict__ pW2,
    const float* __restrict__ pb2, const float* __restrict__ noise,
    int M, int K) {
  __shared__ short AhS[8 * 64 * 8];
  __shared__ short AlS[8 * 64 * 8];
  __shared__ int ehS[64], etS[64];
  __shared__ float plS[256];

  const int tid = threadIdx.x;
  const int w = tid >> 6;
  const int lane31 = tid & 31;
  const int hw = (tid >> 5) & 1;
  const int m0 = blockIdx.x * 64;

  if (EPI == EP_BIAS_SCATTER) {
    if (tid < 64) ehS[tid] = (m0 + tid < M) ? eidx[m0 + tid] : 0;
  }
  if (EPI == EP_EDGE) {
    if (tid < 64) { ehS[tid] = eidx[m0 + tid]; etS[tid] = eidx[E + m0 + tid]; }
  }

  f32x16 acc[2][2];
#pragma unroll
  for (int a = 0; a < 2; a++)
#pragma unroll
    for (int b = 0; b < 2; b++)
#pragma unroll
      for (int i = 0; i < 16; i++) acc[a][b][i] = 0.f;

  const int col0 = (w << 6) + lane31;
  const int col1 = col0 + 32;
  const bf16x8* WhV = (const bf16x8*)Wh;
  const bf16x8* WlV = (const bf16x8*)Wl;
  bf16x8* AhV = (bf16x8*)AhS;
  bf16x8* AlV = (bf16x8*)AlS;
  const int srow = tid >> 3;   // 0..31
  const int skg = tid & 7;

  for (int k0 = 0; k0 < K; k0 += 64) {
    __syncthreads();
    {
      float v[8];
      bf16x8 ph, pl;
      loadA8<AMODE>(A0, A1, hs, rv, M, m0 + srow, k0 + skg * 8, v);
#pragma unroll
      for (int j = 0; j < 8; j++) { short h, lo; split2(v[j], h, lo); ph[j] = h; pl[j] = lo; }
      AhV[skg * 64 + srow] = ph;
      AlV[skg * 64 + srow] = pl;
      loadA8<AMODE>(A0, A1, hs, rv, M, m0 + srow + 32, k0 + skg * 8, v);
#pragma unroll
      for (int j = 0; j < 8; j++) { short h, lo; split2(v[j], h, lo); ph[j] = h; pl[j] = lo; }
      AhV[skg * 64 + srow + 32] = ph;
      AlV[skg * 64 + srow + 32] = pl;
    }
    __syncthreads();
#pragma unroll
    for (int ks = 0; ks < 4; ks++) {
      const int kgl = 2 * ks + hw;
      bf16x8 a0h = AhV[kgl * 64 + lane31];
      bf16x8 a0l = AlV[kgl * 64 + lane31];
      bf16x8 a1h = AhV[kgl * 64 + 32 + lane31];
      bf16x8 a1l = AlV[kgl * 64 + 32 + lane31];
      size_t wi = (size_t)((k0 >> 3) + kgl) * 256;
      bf16x8 b0h = WhV[wi + col0], b0l = WlV[wi + col0];
      bf16x8 b1h = WhV[wi + col1], b1l = WlV[wi + col1];
      acc[0][0] = MFMA(a0h, b0h, acc[0][0]);
      acc[0][0] = MFMA(a0l, b0h, acc[0][0]);
      acc[0][0] = MFMA(a0h, b0l, acc[0][0]);
      acc[0][1] = MFMA(a0h, b1h, acc[0][1]);
      acc[0][1] = MFMA(a0l, b1h, acc[0][1]);
      acc[0][1] = MFMA(a0h, b1l, acc[0][1]);
      acc[1][0] = MFMA(a1h, b0h, acc[1][0]);
      acc[1][0] = MFMA(a1l, b0h, acc[1][0]);
      acc[1][0] = MFMA(a1h, b0l, acc[1][0]);
      acc[1][1] = MFMA(a1h, b1h, acc[1][1]);
      acc[1][1] = MFMA(a1l, b1h, acc[1][1]);
      acc[1][1] = MFMA(a1h, b1l, acc[1][1]);
    }
  }

  if (EPI == EP_RELU_BIAS || EPI == EP_PLAIN) {
    float b0v = bias ? bias[col0] : 0.f;
    float b1v = bias ? bias[col1] : 0.f;
#pragma unroll
    for (int rf = 0; rf < 2; rf++)
#pragma unroll
      for (int g = 0; g < 4; g++)
#pragma unroll
        for (int q = 0; q < 4; q++) {
          int row = m0 + 32 * rf + q + 8 * g + 4 * hw;
          if (row < M) {
            float v0 = acc[rf][0][4 * g + q] + b0v;
            float v1 = acc[rf][1][4 * g + q] + b1v;
            if (EPI == EP_RELU_BIAS) { v0 = fmaxf(v0, 0.f); v1 = fmaxf(v1, 0.f); }
            out[(size_t)row * 256 + col0] = v0;
            out[(size_t)row * 256 + col1] = v1;
          }
        }
  }
  if (EPI == EP_BIAS_SCATTER) {
    float b0v = bias[col0], b1v = bias[col1];
#pragma unroll
    for (int rf = 0; rf < 2; rf++)
#pragma unroll
      for (int g = 0; g < 4; g++)
#pragma unroll
        for (int q = 0; q < 4; q++) {
          int rl = 32 * rf + q + 8 * g + 4 * hw;
          if (m0 + rl < M) {
            float* dst = scat + (size_t)ehS[rl] * 256;
            atomicAdd(dst + col0, acc[rf][0][4 * g + q] + b0v);
            atomicAdd(dst + col1, acc[rf][1][4 * g + q] + b1v);
          }
        }
  }
  if (EPI == EP_EDGE) {
    float qw0 = qW[col0], qw1 = qW[col1];
    float w20 = pW2[col0], w21 = pW2[col1];
#pragma unroll
    for (int rf = 0; rf < 2; rf++) {
      float p[16];
#pragma unroll
      for (int g = 0; g < 4; g++)
#pragma unroll
        for (int q = 0; q < 4; q++) {
          int rl = 32 * rf + q + 8 * g + 4 * hw;
          int hh = ehS[rl], tt = etS[rl];
          float h0 = acc[rf][0][4 * g + q] + qw0 +
                     HEh[(size_t)hh * 256 + col0] + HEt[(size_t)tt * 256 + col0];
          float h1 = acc[rf][1][4 * g + q] + qw1 +
                     HEh[(size_t)hh * 256 + col1] + HEt[(size_t)tt * 256 + col1];
          p[4 * g + q] = fmaxf(h0, 0.f) * w20 + fmaxf(h1, 0.f) * w21;
        }
#pragma unroll
      for (int m = 1; m <= 16; m <<= 1)
#pragma unroll
        for (int i = 0; i < 16; i++) p[i] += __shfl_xor(p[i], m);
      if (lane31 == 0) {
#pragma unroll
        for (int g = 0; g < 4; g++)
#pragma unroll
          for (int q = 0; q < 4; q++)
            plS[w * 64 + 32 * rf + q + 8 * g + 4 * hw] = p[4 * g + q];
      }
    }
    __syncthreads();
    if (tid < 64) {
      float s = plS[tid] + plS[64 + tid] + plS[128 + tid] + plS[192 + tid] + pb2[0];
      int e = m0 + tid;
      float nz = noise[e];
      float rn = logf(nz) - logf(1.f - nz);
      out[e] = s;
      out[E + e] = 1.f / (1.f + expf(-(s + rn)));
    }
  }
}

extern "C" void kernel_launch(void* const* d_in, const int* in_sizes, int n_in,
                              void* d_out, int out_size, void* d_ws, size_t ws_size,
                              hipStream_t stream) {
  const float* entity = (const float*)d_in[0];
  const float* ea     = (const float*)d_in[1];
  const float* q      = (const float*)d_in[2];
  const float* noise  = (const float*)d_in[3];
  const float* W_pr1  = (const float*)d_in[4];
  const float* b_pr1  = (const float*)d_in[5];
  const float* W_pr2  = (const float*)d_in[6];
  const float* b_pr2  = (const float*)d_in[7];
  const float* sW0    = (const float*)d_in[8];
  const float* sb0    = (const float*)d_in[9];
  const float* sW1    = (const float*)d_in[10];
  const float* sb1    = (const float*)d_in[11];
  const float* pW1    = (const float*)d_in[12];
  const float* pb1    = (const float*)d_in[13];
  const float* pW2    = (const float*)d_in[14];
  const float* pb2    = (const float*)d_in[15];
  const void*  ei_raw = d_in[16];

  char* ws = (char*)d_ws;
  const size_t NDB = (size_t)NV * D * 4;   // 51.2 MB
  size_t off = 0;
  float* R    = (float*)(ws + off); off += 4 * NDB;   // 204.8 MB region
  float* hsum = (float*)(ws + off); off += NDB;
  // Wf buffers (hi+lo = K*512 bytes each)
  auto alloc_w = [&](int K) { short* p = (short*)(ws + off); off += (size_t)K * 512; return p; };
  short* Wpr1h = alloc_w(256); short* Wpr1l = alloc_w(256);
  short* Wpr2h = alloc_w(256); short* Wpr2l = alloc_w(256);
  short* sW0h  = alloc_w(512); short* sW0l  = alloc_w(512);
  short* sW1h  = alloc_w(512); short* sW1l  = alloc_w(512);
  short* Whehh = alloc_w(512); short* Whehl = alloc_w(512);
  short* Weah  = alloc_w(256); short* Weal  = alloc_w(256);
  short* Wheth = alloc_w(512); short* Whetl = alloc_w(512);
  float* cnt  = (float*)(ws + off); off += (size_t)NV * 4;
  float* rinv = (float*)(ws + off); off += (size_t)NV * 4;
  float* qW   = (float*)(ws + off); off += 1024;
  int*   ei32 = (int*)(ws + off);   off += (size_t)TWOE * 4;
  int*   flag = (int*)(ws + off);   off += 64;

  // aliases within R (lifetimes disjoint with tmp1)
  float* tmp1 = R;            // [E x 256] f32, live G1->G2
  float* xsum = R;            // live after G2
  float* out0 = R + NDB / 4;  // (float count offset)
  float* out1 = R + 2 * (NDB / 4);
  float* HEt  = R + 3 * (NDB / 4);
  float* HEh  = hsum;         // hsum dead after G4

  hipMemsetAsync(hsum, 0, NDB, stream);
  hipMemsetAsync(cnt, 0, (size_t)NV * 4, stream);
  k_detect<<<1, 256, 0, stream>>>(ei_raw, flag);
  k_convert<<<(TWOE + 255) / 256, 256, 0, stream>>>(ei_raw, flag, ei32);
  k_fwd_scatter<<<E / 4, 256, 0, stream>>>(ea, ei32, hsum, cnt);
  k_rinv<<<(NV + 255) / 256, 256, 0, stream>>>(cnt, rinv);

  k_wprep<<<256 / 32, 256, 0, stream>>>(W_pr1, Wpr1h, Wpr1l);
  k_wprep<<<256 / 32, 256, 0, stream>>>(W_pr2, Wpr2h, Wpr2l);
  k_wprep<<<512 / 32, 256, 0, stream>>>(sW0, sW0h, sW0l);
  k_wprep<<<512 / 32, 256, 0, stream>>>(sW1, sW1h, sW1l);
  k_wprep<<<512 / 32, 256, 0, stream>>>(pW1 + 256 * 256, Whehh, Whehl);
  k_wprep<<<256 / 32, 256, 0, stream>>>(pW1 + 768 * 256, Weah, Weal);
  k_wprep<<<512 / 32, 256, 0, stream>>>(pW1 + 1024 * 256, Wheth, Whetl);

  // G1: tmp1 = relu(ea @ Wpr1 + b_pr1)
  k_gemm<A_SINGLE, EP_RELU_BIAS><<<E / 64, 256, 0, stream>>>(
      ea, nullptr, nullptr, nullptr, Wpr1h, Wpr1l, b_pr1, tmp1,
      nullptr, nullptr, nullptr, nullptr, nullptr, nullptr, nullptr, nullptr, E, 256);
  // G2: hsum[h_e] += tmp1 @ Wpr2 + b_pr2
  k_gemm<A_SINGLE, EP_BIAS_SCATTER><<<E / 64, 256, 0, stream>>>(
      tmp1, nullptr, nullptr, nullptr, Wpr2h, Wpr2l, b_pr2, nullptr,
      ei32, hsum, nullptr, nullptr, nullptr, nullptr, nullptr, nullptr, E, 256);

  // layer 0
  hipMemsetAsync(xsum, 0, NDB, stream);
  k_xscatter<<<TWOE / 4, 256, 0, stream>>>(entity, ei32, xsum);
  k_gemm<A_DUAL_AGG, EP_RELU_BIAS><<<(NV + 63) / 64, 256, 0, stream>>>(
      entity, xsum, hsum, rinv, sW0h, sW0l, sb0, out0,
      nullptr, nullptr, nullptr, nullptr, nullptr, nullptr, nullptr, nullptr, NV, 512);
  // layer 1
  hipMemsetAsync(xsum, 0, NDB, stream);
  k_xscatter<<<TWOE / 4, 256, 0, stream>>>(out0, ei32, xsum);
  k_gemm<A_DUAL_AGG, EP_RELU_BIAS><<<(NV + 63) / 64, 256, 0, stream>>>(
      out0, xsum, hsum, rinv, sW1h, sW1l, sb1, out1,
      nullptr, nullptr, nullptr, nullptr, nullptr, nullptr, nullptr, nullptr, NV, 512);

  // HEh = [out0|out1] @ pW1[256:768]   (into hsum buffer, hsum now dead)
  k_gemm<A_DUAL, EP_PLAIN><<<(NV + 63) / 64, 256, 0, stream>>>(
      out0, out1, nullptr, nullptr, Whehh, Whehl, nullptr, HEh,
      nullptr, nullptr, nullptr, nullptr, nullptr, nullptr, nullptr, nullptr, NV, 512);
  // HEt = [out0|out1] @ pW1[1024:1536]
  k_gemm<A_DUAL, EP_PLAIN><<<(NV + 63) / 64, 256, 0, stream>>>(
      out0, out1, nullptr, nullptr, Wheth, Whetl, nullptr, HEt,
      nullptr, nullptr, nullptr, nullptr, nullptr, nullptr, nullptr, nullptr, NV, 512);

  k_qw<<<1, 256, 0, stream>>>(q, pW1, pb1, qW);

  // fused: EA2 GEMM + per-edge combine + w2-dot + sampling
  k_gemm<A_SINGLE, EP_EDGE><<<E / 64, 256, 0, stream>>>(
      ea, nullptr, nullptr, nullptr, Weah, Weal, nullptr, (float*)d_out,
      ei32, nullptr, HEh, HEt, qW, pW2, pb2, noise, E, 256);
}

// Round 3
// 1106.776 us; speedup vs baseline: 6.4368x; 3.8806x over previous
//
#include <hip/hip_runtime.h>
#include <math.h>

// FineGrainedRetriever round 3: atomic-free. CSR (dst-keyed) built once; all
// segment sums are gathers. Reverse-edge proj scatter collapsed algebraically:
// sum_h(relu(ea@W1+b1)@W2+b2) = (sum_h hid)@W2 + degrev*b2  (NV-row GEMM).
// GEMMs remain split-bf16 MFMA (3x mfma_32x32x16 per tile).

namespace {
constexpr int E    = 200000;
constexpr int NV   = 50000;
constexpr int D    = 256;
constexpr int TWOE = 2 * E;
}

typedef __attribute__((ext_vector_type(8))) short bf16x8;
typedef __attribute__((ext_vector_type(16))) float f32x16;

#define MFMA(a, b, c) __builtin_amdgcn_mfma_f32_32x32x16_bf16((a), (b), (c), 0, 0, 0)

__device__ inline void split2(float x, short& h, short& lo) {
  unsigned u = __float_as_uint(x);
  unsigned hb = u & 0xffff0000u;
  h = (short)(hb >> 16);
  float r = x - __uint_as_float(hb);   // exact
  lo = (short)(__float_as_uint(r) >> 16);
}

// ---- edge_index dtype probe (int64 vs int32) -------------------------------
__global__ void k_detect(const void* ei_raw, int* flag) {
  __shared__ int bad;
  if (threadIdx.x == 0) bad = 0;
  __syncthreads();
  const long long* p = (const long long*)ei_raw;
  long long v = p[threadIdx.x];
  if (v < 0 || v >= (long long)NV) atomicOr(&bad, 1);
  __syncthreads();
  if (threadIdx.x == 0) *flag = bad ? 0 : 1;  // 1 => int64
}

__global__ void k_convert(const void* ei_raw, const int* __restrict__ flag,
                          int* __restrict__ ei32) {
  int i = blockIdx.x * 256 + threadIdx.x;
  if (i >= TWOE) return;
  if (*flag) ei32[i] = (int)((const long long*)ei_raw)[i];
  else       ei32[i] = ((const int*)ei_raw)[i];
}

// ---- CSR build -------------------------------------------------------------
__global__ void k_deg(const int* __restrict__ ei32, int* __restrict__ deg) {
  int de = blockIdx.x * 256 + threadIdx.x;
  if (de >= TWOE) return;
  int dst = (de < E) ? ei32[E + de] : ei32[de - E];
  atomicAdd(&deg[dst], 1);
}

__global__ __launch_bounds__(1024) void k_scan(const int* __restrict__ deg,
                                               int* __restrict__ off) {
  __shared__ int wsum[16];
  __shared__ int carryS;
  int tid = threadIdx.x;
  int lane = tid & 63, wv = tid >> 6;
  if (tid == 0) carryS = 0;
  __syncthreads();
  for (int base = 0; base < NV; base += 1024) {
    int i = base + tid;
    int v = (i < NV) ? deg[i] : 0;
    int s = v;
#pragma unroll
    for (int d = 1; d < 64; d <<= 1) {
      int t = __shfl_up(s, d);
      if (lane >= d) s += t;
    }
    if (lane == 63) wsum[wv] = s;
    int carry = carryS;
    __syncthreads();
    if (wv == 0) {
      int ws = (lane < 16) ? wsum[lane] : 0;
#pragma unroll
      for (int d = 1; d < 16; d <<= 1) {
        int t = __shfl_up(ws, d);
        if (lane >= d) ws += t;
      }
      if (lane < 16) wsum[lane] = ws;
    }
    __syncthreads();
    int wexcl = (wv == 0) ? 0 : wsum[wv - 1];
    if (i < NV) off[i] = carry + wexcl + s - v;
    if (tid == 1023) carryS = carry + wsum[15];
    __syncthreads();
  }
  if (tid == 0) off[NV] = carryS;
}

__global__ void k_fill(const int* __restrict__ ei32, const int* __restrict__ off,
                       int* __restrict__ cursor, int* __restrict__ eidA,
                       int* __restrict__ srcA) {
  int de = blockIdx.x * 256 + threadIdx.x;
  if (de >= TWOE) return;
  int dst = (de < E) ? ei32[E + de] : ei32[de - E];
  int p = atomicAdd(&cursor[dst], 1);
  int idx = off[dst] + p;
  eidA[idx] = de;
  srcA[idx] = ei32[de];
}

__global__ void k_rinv(const int* __restrict__ off, float* __restrict__ rinv) {
  int n = blockIdx.x * 256 + threadIdx.x;
  if (n < NV) {
    int d = off[n + 1] - off[n];
    rinv[n] = 1.f / fmaxf((float)d, 1.f);
  }
}

// ---- gather: hsum_fwd[n] = sum ea rows; hidsum[n] = sum hid rows; degrev ---
__global__ __launch_bounds__(256) void k_gath_h(
    const float* __restrict__ ea, const float* __restrict__ tmp1,
    const int* __restrict__ eidA, const int* __restrict__ off,
    float* __restrict__ hsum, float* __restrict__ hidsum,
    float* __restrict__ degrev) {
  int n = blockIdx.x * 4 + (threadIdx.x >> 6);
  if (n >= NV) return;
  int l = threadIdx.x & 63;
  float4 fs = {0.f, 0.f, 0.f, 0.f}, hv = {0.f, 0.f, 0.f, 0.f};
  int o0 = off[n], o1 = off[n + 1];
  int dr = 0;
  for (int j = o0; j < o1; j++) {
    int de = eidA[j];
    if (de < E) {
      float4 v = ((const float4*)(ea + (size_t)de * D))[l];
      fs.x += v.x; fs.y += v.y; fs.z += v.z; fs.w += v.w;
    } else {
      float4 v = ((const float4*)(tmp1 + (size_t)(de - E) * D))[l];
      hv.x += v.x; hv.y += v.y; hv.z += v.z; hv.w += v.w;
      dr++;
    }
  }
  ((float4*)(hsum + (size_t)n * D))[l] = fs;
  ((float4*)(hidsum + (size_t)n * D))[l] = hv;
  if (l == 0) degrev[n] = (float)dr;
}

// ---- per-layer aggregate: agg[n] = (sum_j x[src_j] + hsum[n]) * rinv[n] ----
__global__ __launch_bounds__(256) void k_agg(
    const float* __restrict__ x, const int* __restrict__ srcA,
    const int* __restrict__ off, const float* __restrict__ hsum,
    const float* __restrict__ rinv, float* __restrict__ agg) {
  int n = blockIdx.x * 4 + (threadIdx.x >> 6);
  if (n >= NV) return;
  int l = threadIdx.x & 63;
  float4 s = ((const float4*)(hsum + (size_t)n * D))[l];
  int o0 = off[n], o1 = off[n + 1];
  for (int j = o0; j < o1; j++) {
    int src = srcA[j];
    float4 v = ((const float4*)(x + (size_t)src * D))[l];
    s.x += v.x; s.y += v.y; s.z += v.z; s.w += v.w;
  }
  float r = rinv[n];
  float4 o = {s.x * r, s.y * r, s.z * r, s.w * r};
  ((float4*)(agg + (size_t)n * D))[l] = o;
}

// ---- weight prep: W[K][256] f32 -> Wf_hi/Wf_lo [K/8][256][8] bf16 ----------
__global__ __launch_bounds__(256) void k_wprep(const float* __restrict__ W,
                                               short* __restrict__ Wh,
                                               short* __restrict__ Wl) {
  __shared__ float tl[32][260];
  int tid = threadIdx.x;
  int k0 = blockIdx.x * 32;
#pragma unroll
  for (int i = 0; i < 32; i++) tl[i][tid] = W[(size_t)(k0 + i) * 256 + tid];
  __syncthreads();
  bf16x8* WhV = (bf16x8*)Wh;
  bf16x8* WlV = (bf16x8*)Wl;
#pragma unroll
  for (int kg = 0; kg < 4; kg++) {
    bf16x8 ph, pl;
#pragma unroll
    for (int j = 0; j < 8; j++) {
      short h, lo;
      split2(tl[kg * 8 + j][tid], h, lo);
      ph[j] = h; pl[j] = lo;
    }
    WhV[(size_t)((k0 >> 3) + kg) * 256 + tid] = ph;
    WlV[(size_t)((k0 >> 3) + kg) * 256 + tid] = pl;
  }
}

// ---- qW[n] = q @ pred_W1[:256,n] + pred_b1[n] ------------------------------
__global__ void k_qw(const float* __restrict__ q, const float* __restrict__ W1,
                     const float* __restrict__ b1, float* __restrict__ qW) {
  __shared__ float ql[D];
  int n = threadIdx.x;
  ql[n] = q[n];
  __syncthreads();
  float s = b1[n];
  for (int k = 0; k < D; k++) s += ql[k] * W1[(size_t)k * D + n];
  qW[n] = s;
}

// ---- generic MFMA GEMM: out = epi(A[M x K] @ Wf + ...), N=256 --------------
enum AM { A_SINGLE, A_DUAL };
enum EP { EP_RELU_BIAS, EP_PLAIN, EP_ADDC, EP_EDGE };

template<int AMODE>
__device__ inline void loadA8(const float* __restrict__ A0, const float* __restrict__ A1,
                              int M, int row, int k, float* v) {
  if (row >= M) {
#pragma unroll
    for (int j = 0; j < 8; j++) v[j] = 0.f;
    return;
  }
  const float* src = (AMODE == A_SINGLE || k < 256) ? (A0 + (size_t)row * 256 + k)
                                                    : (A1 + (size_t)row * 256 + (k - 256));
  const float4* p = (const float4*)src;
  float4 a = p[0], b = p[1];
  v[0] = a.x; v[1] = a.y; v[2] = a.z; v[3] = a.w;
  v[4] = b.x; v[5] = b.y; v[6] = b.z; v[7] = b.w;
}

template<int AMODE, int EPI>
__global__ __launch_bounds__(256) void k_gemm(
    const float* __restrict__ A0, const float* __restrict__ A1,
    const float* __restrict__ addm, const float* __restrict__ rv,
    const short* __restrict__ Wh, const short* __restrict__ Wl,
    const float* __restrict__ bias, float* __restrict__ out,
    const int* __restrict__ eidx,
    const float* __restrict__ HEh, const float* __restrict__ HEt,
    const float* __restrict__ qW, const float* __restrict__ pW2,
    const float* __restrict__ pb2, const float* __restrict__ noise,
    int M, int K) {
  __shared__ short AhS[8 * 64 * 8];
  __shared__ short AlS[8 * 64 * 8];
  __shared__ int ehS[64], etS[64];
  __shared__ float plS[256];

  const int tid = threadIdx.x;
  const int w = tid >> 6;
  const int lane31 = tid & 31;
  const int hw = (tid >> 5) & 1;
  const int m0 = blockIdx.x * 64;

  if (EPI == EP_EDGE) {
    if (tid < 64) { ehS[tid] = eidx[m0 + tid]; etS[tid] = eidx[E + m0 + tid]; }
  }

  f32x16 acc[2][2];
#pragma unroll
  for (int a = 0; a < 2; a++)
#pragma unroll
    for (int b = 0; b < 2; b++)
#pragma unroll
      for (int i = 0; i < 16; i++) acc[a][b][i] = 0.f;

  const int col0 = (w << 6) + lane31;
  const int col1 = col0 + 32;
  const bf16x8* WhV = (const bf16x8*)Wh;
  const bf16x8* WlV = (const bf16x8*)Wl;
  bf16x8* AhV = (bf16x8*)AhS;
  bf16x8* AlV = (bf16x8*)AlS;
  const int srow = tid >> 3;
  const int skg = tid & 7;

  for (int k0 = 0; k0 < K; k0 += 64) {
    __syncthreads();
    {
      float v[8];
      bf16x8 ph, pl;
      loadA8<AMODE>(A0, A1, M, m0 + srow, k0 + skg * 8, v);
#pragma unroll
      for (int j = 0; j < 8; j++) { short h, lo; split2(v[j], h, lo); ph[j] = h; pl[j] = lo; }
      AhV[skg * 64 + srow] = ph;
      AlV[skg * 64 + srow] = pl;
      loadA8<AMODE>(A0, A1, M, m0 + srow + 32, k0 + skg * 8, v);
#pragma unroll
      for (int j = 0; j < 8; j++) { short h, lo; split2(v[j], h, lo); ph[j] = h; pl[j] = lo; }
      AhV[skg * 64 + srow + 32] = ph;
      AlV[skg * 64 + srow + 32] = pl;
    }
    __syncthreads();
#pragma unroll
    for (int ks = 0; ks < 4; ks++) {
      const int kgl = 2 * ks + hw;
      bf16x8 a0h = AhV[kgl * 64 + lane31];
      bf16x8 a0l = AlV[kgl * 64 + lane31];
      bf16x8 a1h = AhV[kgl * 64 + 32 + lane31];
      bf16x8 a1l = AlV[kgl * 64 + 32 + lane31];
      size_t wi = (size_t)((k0 >> 3) + kgl) * 256;
      bf16x8 b0h = WhV[wi + col0], b0l = WlV[wi + col0];
      bf16x8 b1h = WhV[wi + col1], b1l = WlV[wi + col1];
      acc[0][0] = MFMA(a0h, b0h, acc[0][0]);
      acc[0][0] = MFMA(a0l, b0h, acc[0][0]);
      acc[0][0] = MFMA(a0h, b0l, acc[0][0]);
      acc[0][1] = MFMA(a0h, b1h, acc[0][1]);
      acc[0][1] = MFMA(a0l, b1h, acc[0][1]);
      acc[0][1] = MFMA(a0h, b1l, acc[0][1]);
      acc[1][0] = MFMA(a1h, b0h, acc[1][0]);
      acc[1][0] = MFMA(a1l, b0h, acc[1][0]);
      acc[1][0] = MFMA(a1h, b0l, acc[1][0]);
      acc[1][1] = MFMA(a1h, b1h, acc[1][1]);
      acc[1][1] = MFMA(a1l, b1h, acc[1][1]);
      acc[1][1] = MFMA(a1h, b1l, acc[1][1]);
    }
  }

  if (EPI == EP_RELU_BIAS || EPI == EP_PLAIN) {
    float b0v = bias ? bias[col0] : 0.f;
    float b1v = bias ? bias[col1] : 0.f;
#pragma unroll
    for (int rf = 0; rf < 2; rf++)
#pragma unroll
      for (int g = 0; g < 4; g++)
#pragma unroll
        for (int q = 0; q < 4; q++) {
          int row = m0 + 32 * rf + q + 8 * g + 4 * hw;
          if (row < M) {
            float v0 = acc[rf][0][4 * g + q] + b0v;
            float v1 = acc[rf][1][4 * g + q] + b1v;
            if (EPI == EP_RELU_BIAS) { v0 = fmaxf(v0, 0.f); v1 = fmaxf(v1, 0.f); }
            out[(size_t)row * 256 + col0] = v0;
            out[(size_t)row * 256 + col1] = v1;
          }
        }
  }
  if (EPI == EP_ADDC) {
    // out = acc + addm + rv[row]*bias   (in-place safe: 1 thread per element)
    float b0v = bias[col0], b1v = bias[col1];
#pragma unroll
    for (int rf = 0; rf < 2; rf++)
#pragma unroll
      for (int g = 0; g < 4; g++)
#pragma unroll
        for (int q = 0; q < 4; q++) {
          int row = m0 + 32 * rf + q + 8 * g + 4 * hw;
          if (row < M) {
            float dr = rv[row];
            out[(size_t)row * 256 + col0] =
                acc[rf][0][4 * g + q] + addm[(size_t)row * 256 + col0] + dr * b0v;
            out[(size_t)row * 256 + col1] =
                acc[rf][1][4 * g + q] + addm[(size_t)row * 256 + col1] + dr * b1v;
          }
        }
  }
  if (EPI == EP_EDGE) {
    float qw0 = qW[col0], qw1 = qW[col1];
    float w20 = pW2[col0], w21 = pW2[col1];
#pragma unroll
    for (int rf = 0; rf < 2; rf++) {
      float p[16];
#pragma unroll
      for (int g = 0; g < 4; g++)
#pragma unroll
        for (int q = 0; q < 4; q++) {
          int rl = 32 * rf + q + 8 * g + 4 * hw;
          int hh = ehS[rl], tt = etS[rl];
          float h0 = acc[rf][0][4 * g + q] + qw0 +
                     HEh[(size_t)hh * 256 + col0] + HEt[(size_t)tt * 256 + col0];
          float h1 = acc[rf][1][4 * g + q] + qw1 +
                     HEh[(size_t)hh * 256 + col1] + HEt[(size_t)tt * 256 + col1];
          p[4 * g + q] = fmaxf(h0, 0.f) * w20 + fmaxf(h1, 0.f) * w21;
        }
#pragma unroll
      for (int m = 1; m <= 16; m <<= 1)
#pragma unroll
        for (int i = 0; i < 16; i++) p[i] += __shfl_xor(p[i], m);
      if (lane31 == 0) {
#pragma unroll
        for (int g = 0; g < 4; g++)
#pragma unroll
          for (int q = 0; q < 4; q++)
            plS[w * 64 + 32 * rf + q + 8 * g + 4 * hw] = p[4 * g + q];
      }
    }
    __syncthreads();
    if (tid < 64) {
      float s = plS[tid] + plS[64 + tid] + plS[128 + tid] + plS[192 + tid] + pb2[0];
      int e = m0 + tid;
      float nz = noise[e];
      float rn = logf(nz) - logf(1.f - nz);
      out[e] = s;
      out[E + e] = 1.f / (1.f + expf(-(s + rn)));
    }
  }
}

extern "C" void kernel_launch(void* const* d_in, const int* in_sizes, int n_in,
                              void* d_out, int out_size, void* d_ws, size_t ws_size,
                              hipStream_t stream) {
  const float* entity = (const float*)d_in[0];
  const float* ea     = (const float*)d_in[1];
  const float* q      = (const float*)d_in[2];
  const float* noise  = (const float*)d_in[3];
  const float* W_pr1  = (const float*)d_in[4];
  const float* b_pr1  = (const float*)d_in[5];
  const float* W_pr2  = (const float*)d_in[6];
  const float* b_pr2  = (const float*)d_in[7];
  const float* sW0    = (const float*)d_in[8];
  const float* sb0    = (const float*)d_in[9];
  const float* sW1    = (const float*)d_in[10];
  const float* sb1    = (const float*)d_in[11];
  const float* pW1    = (const float*)d_in[12];
  const float* pb1    = (const float*)d_in[13];
  const float* pW2    = (const float*)d_in[14];
  const float* pb2    = (const float*)d_in[15];
  const void*  ei_raw = d_in[16];

  char* ws = (char*)d_ws;
  const size_t NDB = (size_t)NV * D * 4;   // 51.2 MB
  const size_t NDF = NDB / 4;              // floats per [NV x 256]
  size_t off_b = 0;
  float* R      = (float*)(ws + off_b); off_b += 4 * NDB;  // tmp1 region (E x 256)
  float* hsum   = (float*)(ws + off_b); off_b += NDB;
  float* hidsum = (float*)(ws + off_b); off_b += NDB;
  auto alloc_w = [&](int K) { short* p = (short*)(ws + off_b); off_b += (size_t)K * 512; return p; };
  short* Wpr1h = alloc_w(256); short* Wpr1l = alloc_w(256);
  short* Wpr2h = alloc_w(256); short* Wpr2l = alloc_w(256);
  short* sW0h  = alloc_w(512); short* sW0l  = alloc_w(512);
  short* sW1h  = alloc_w(512); short* sW1l  = alloc_w(512);
  short* Whehh = alloc_w(512); short* Whehl = alloc_w(512);
  short* Weah  = alloc_w(256); short* Weal  = alloc_w(256);
  short* Wheth = alloc_w(512); short* Whetl = alloc_w(512);
  float* rinv   = (float*)(ws + off_b); off_b += (size_t)NV * 4;
  float* degrev = (float*)(ws + off_b); off_b += (size_t)NV * 4;
  float* qW     = (float*)(ws + off_b); off_b += 1024;
  int*   ei32   = (int*)(ws + off_b);   off_b += (size_t)TWOE * 4;
  int*   eidA   = (int*)(ws + off_b);   off_b += (size_t)TWOE * 4;
  int*   srcA   = (int*)(ws + off_b);   off_b += (size_t)TWOE * 4;
  int*   offA   = (int*)(ws + off_b);   off_b += (size_t)(NV + 1) * 4;
  int*   deg    = (int*)(ws + off_b);   off_b += (size_t)NV * 4;
  int*   cursor = (int*)(ws + off_b);   off_b += (size_t)NV * 4;
  int*   flag   = (int*)(ws + off_b);   off_b += 64;

  // region-R aliases (tmp1 dead after k_gath_h)
  float* tmp1 = R;              // [E x 256]
  float* agg  = R;              // [NV x 256]
  float* out0 = R + NDF;
  float* out1 = R + 2 * NDF;
  float* HEt  = R + 3 * NDF;
  float* HEh  = hidsum;         // hidsum dead after EP_ADDC GEMM

  // ---- indices & CSR ----
  k_detect<<<1, 256, 0, stream>>>(ei_raw, flag);
  k_convert<<<(TWOE + 255) / 256, 256, 0, stream>>>(ei_raw, flag, ei32);
  hipMemsetAsync(deg, 0, (size_t)NV * 4, stream);
  hipMemsetAsync(cursor, 0, (size_t)NV * 4, stream);
  k_deg<<<(TWOE + 255) / 256, 256, 0, stream>>>(ei32, deg);
  k_scan<<<1, 1024, 0, stream>>>(deg, offA);
  k_fill<<<(TWOE + 255) / 256, 256, 0, stream>>>(ei32, offA, cursor, eidA, srcA);
  k_rinv<<<(NV + 255) / 256, 256, 0, stream>>>(offA, rinv);

  // ---- weight prep ----
  k_wprep<<<256 / 32, 256, 0, stream>>>(W_pr1, Wpr1h, Wpr1l);
  k_wprep<<<256 / 32, 256, 0, stream>>>(W_pr2, Wpr2h, Wpr2l);
  k_wprep<<<512 / 32, 256, 0, stream>>>(sW0, sW0h, sW0l);
  k_wprep<<<512 / 32, 256, 0, stream>>>(sW1, sW1h, sW1l);
  k_wprep<<<512 / 32, 256, 0, stream>>>(pW1 + 256 * 256, Whehh, Whehl);
  k_wprep<<<256 / 32, 256, 0, stream>>>(pW1 + 768 * 256, Weah, Weal);
  k_wprep<<<512 / 32, 256, 0, stream>>>(pW1 + 1024 * 256, Wheth, Whetl);

  // ---- proj: tmp1 = relu(ea @ Wpr1 + b_pr1) ----
  k_gemm<A_SINGLE, EP_RELU_BIAS><<<E / 64, 256, 0, stream>>>(
      ea, nullptr, nullptr, nullptr, Wpr1h, Wpr1l, b_pr1, tmp1,
      nullptr, nullptr, nullptr, nullptr, nullptr, nullptr, nullptr, E, 256);
  // gather: hsum = sum_fwd ea; hidsum = sum_rev hid; degrev
  k_gath_h<<<(NV + 3) / 4, 256, 0, stream>>>(ea, tmp1, eidA, offA, hsum, hidsum, degrev);
  // hsum += hidsum @ Wpr2 + degrev*b_pr2   (in-place)
  k_gemm<A_SINGLE, EP_ADDC><<<(NV + 63) / 64, 256, 0, stream>>>(
      hidsum, nullptr, hsum, degrev, Wpr2h, Wpr2l, b_pr2, hsum,
      nullptr, nullptr, nullptr, nullptr, nullptr, nullptr, nullptr, NV, 256);

  // ---- layer 0 ----
  k_agg<<<(NV + 3) / 4, 256, 0, stream>>>(entity, srcA, offA, hsum, rinv, agg);
  k_gemm<A_DUAL, EP_RELU_BIAS><<<(NV + 63) / 64, 256, 0, stream>>>(
      entity, agg, nullptr, nullptr, sW0h, sW0l, sb0, out0,
      nullptr, nullptr, nullptr, nullptr, nullptr, nullptr, nullptr, NV, 512);
  // ---- layer 1 ----
  k_agg<<<(NV + 3) / 4, 256, 0, stream>>>(out0, srcA, offA, hsum, rinv, agg);
  k_gemm<A_DUAL, EP_RELU_BIAS><<<(NV + 63) / 64, 256, 0, stream>>>(
      out0, agg, nullptr, nullptr, sW1h, sW1l, sb1, out1,
      nullptr, nullptr, nullptr, nullptr, nullptr, nullptr, nullptr, NV, 512);

  // ---- pred node-side GEMMs ----
  k_gemm<A_DUAL, EP_PLAIN><<<(NV + 63) / 64, 256, 0, stream>>>(
      out0, out1, nullptr, nullptr, Whehh, Whehl, nullptr, HEh,
      nullptr, nullptr, nullptr, nullptr, nullptr, nullptr, nullptr, NV, 512);
  k_gemm<A_DUAL, EP_PLAIN><<<(NV + 63) / 64, 256, 0, stream>>>(
      out0, out1, nullptr, nullptr, Wheth, Whetl, nullptr, HEt,
      nullptr, nullptr, nullptr, nullptr, nullptr, nullptr, nullptr, NV, 512);

  k_qw<<<1, 256, 0, stream>>>(q, pW1, pb1, qW);

  // ---- fused: EA2 GEMM + per-edge combine + w2-dot + sampling ----
  k_gemm<A_SINGLE, EP_EDGE><<<E / 64, 256, 0, stream>>>(
      ea, nullptr, nullptr, nullptr, Weah, Weal, nullptr, (float*)d_out,
      ei32, HEh, HEt, qW, pW2, pb2, noise, E, 256);
}

// Round 4
// 1067.906 us; speedup vs baseline: 6.6710x; 1.0364x over previous
//
#include <hip/hip_runtime.h>
#include <math.h>

// FineGrainedRetriever round 4: f16 intermediates for all gather-consumed
// buffers (tmp1, HEh/HEt, entity/out0 shadows) + vectorized EP_EDGE epilogue
// (LDS-staged EA2 tile, f16x4 lane-per-4-cols gathers, 1 shuffle-reduce/edge).
// GEMM core unchanged: split-bf16 hi/lo, 3x mfma_32x32x16 per tile.

namespace {
constexpr int E    = 200000;
constexpr int NV   = 50000;
constexpr int D    = 256;
constexpr int TWOE = 2 * E;
}

typedef __attribute__((ext_vector_type(8))) short bf16x8;
typedef __attribute__((ext_vector_type(16))) float f32x16;
typedef __attribute__((ext_vector_type(4))) _Float16 f16x4;
typedef __attribute__((ext_vector_type(8))) _Float16 f16x8;

#define MFMA(a, b, c) __builtin_amdgcn_mfma_f32_32x32x16_bf16((a), (b), (c), 0, 0, 0)

__device__ inline void split2(float x, short& h, short& lo) {
  unsigned u = __float_as_uint(x);
  unsigned hb = u & 0xffff0000u;
  h = (short)(hb >> 16);
  float r = x - __uint_as_float(hb);   // exact
  lo = (short)(__float_as_uint(r) >> 16);
}

// ---- edge_index dtype probe (int64 vs int32) -------------------------------
__global__ void k_detect(const void* ei_raw, int* flag) {
  __shared__ int bad;
  if (threadIdx.x == 0) bad = 0;
  __syncthreads();
  const long long* p = (const long long*)ei_raw;
  long long v = p[threadIdx.x];
  if (v < 0 || v >= (long long)NV) atomicOr(&bad, 1);
  __syncthreads();
  if (threadIdx.x == 0) *flag = bad ? 0 : 1;  // 1 => int64
}

__global__ void k_convert(const void* ei_raw, const int* __restrict__ flag,
                          int* __restrict__ ei32) {
  int i = blockIdx.x * 256 + threadIdx.x;
  if (i >= TWOE) return;
  if (*flag) ei32[i] = (int)((const long long*)ei_raw)[i];
  else       ei32[i] = ((const int*)ei_raw)[i];
}

// ---- CSR build -------------------------------------------------------------
__global__ void k_deg(const int* __restrict__ ei32, int* __restrict__ deg) {
  int de = blockIdx.x * 256 + threadIdx.x;
  if (de >= TWOE) return;
  int dst = (de < E) ? ei32[E + de] : ei32[de - E];
  atomicAdd(&deg[dst], 1);
}

__global__ __launch_bounds__(1024) void k_scan(const int* __restrict__ deg,
                                               int* __restrict__ off) {
  __shared__ int wsum[16];
  __shared__ int carryS;
  int tid = threadIdx.x;
  int lane = tid & 63, wv = tid >> 6;
  if (tid == 0) carryS = 0;
  __syncthreads();
  for (int base = 0; base < NV; base += 1024) {
    int i = base + tid;
    int v = (i < NV) ? deg[i] : 0;
    int s = v;
#pragma unroll
    for (int d = 1; d < 64; d <<= 1) {
      int t = __shfl_up(s, d);
      if (lane >= d) s += t;
    }
    if (lane == 63) wsum[wv] = s;
    int carry = carryS;
    __syncthreads();
    if (wv == 0) {
      int ws = (lane < 16) ? wsum[lane] : 0;
#pragma unroll
      for (int d = 1; d < 16; d <<= 1) {
        int t = __shfl_up(ws, d);
        if (lane >= d) ws += t;
      }
      if (lane < 16) wsum[lane] = ws;
    }
    __syncthreads();
    int wexcl = (wv == 0) ? 0 : wsum[wv - 1];
    if (i < NV) off[i] = carry + wexcl + s - v;
    if (tid == 1023) carryS = carry + wsum[15];
    __syncthreads();
  }
  if (tid == 0) off[NV] = carryS;
}

__global__ void k_fill(const int* __restrict__ ei32, const int* __restrict__ off,
                       int* __restrict__ cursor, int* __restrict__ eidA,
                       int* __restrict__ srcA) {
  int de = blockIdx.x * 256 + threadIdx.x;
  if (de >= TWOE) return;
  int dst = (de < E) ? ei32[E + de] : ei32[de - E];
  int p = atomicAdd(&cursor[dst], 1);
  int idx = off[dst] + p;
  eidA[idx] = de;
  srcA[idx] = ei32[de];
}

__global__ void k_rinv(const int* __restrict__ off, float* __restrict__ rinv) {
  int n = blockIdx.x * 256 + threadIdx.x;
  if (n < NV) {
    int d = off[n + 1] - off[n];
    rinv[n] = 1.f / fmaxf((float)d, 1.f);
  }
}

// ---- f32 -> f16 copy (8 elems/thread) --------------------------------------
__global__ void k_conv16(const float* __restrict__ x, _Float16* __restrict__ y,
                         int n8) {
  int i = blockIdx.x * 256 + threadIdx.x;
  if (i >= n8) return;
  const float4* p = (const float4*)x;
  float4 a = p[2 * i], b = p[2 * i + 1];
  f16x8 o;
  o[0] = (_Float16)a.x; o[1] = (_Float16)a.y; o[2] = (_Float16)a.z; o[3] = (_Float16)a.w;
  o[4] = (_Float16)b.x; o[5] = (_Float16)b.y; o[6] = (_Float16)b.z; o[7] = (_Float16)b.w;
  ((f16x8*)y)[i] = o;
}

// ---- gather: hsum[n] = sum fwd ea rows; hidsum[n] = sum rev hid; degrev ----
__global__ __launch_bounds__(256) void k_gath_h(
    const float* __restrict__ ea, const _Float16* __restrict__ tmp16,
    const int* __restrict__ eidA, const int* __restrict__ off,
    float* __restrict__ hsum, float* __restrict__ hidsum,
    float* __restrict__ degrev) {
  int n = blockIdx.x * 4 + (threadIdx.x >> 6);
  if (n >= NV) return;
  int l = threadIdx.x & 63;
  float4 fs = {0.f, 0.f, 0.f, 0.f}, hv = {0.f, 0.f, 0.f, 0.f};
  int o0 = off[n], o1 = off[n + 1];
  int dr = 0;
  for (int j = o0; j < o1; j++) {
    int de = eidA[j];
    if (de < E) {
      float4 v = ((const float4*)(ea + (size_t)de * D))[l];
      fs.x += v.x; fs.y += v.y; fs.z += v.z; fs.w += v.w;
    } else {
      f16x4 v = ((const f16x4*)(tmp16 + (size_t)(de - E) * D))[l];
      hv.x += (float)v[0]; hv.y += (float)v[1];
      hv.z += (float)v[2]; hv.w += (float)v[3];
      dr++;
    }
  }
  ((float4*)(hsum + (size_t)n * D))[l] = fs;
  ((float4*)(hidsum + (size_t)n * D))[l] = hv;
  if (l == 0) degrev[n] = (float)dr;
}

// ---- per-layer aggregate: agg[n] = (sum_j x16[src_j] + hsum[n]) * rinv[n] --
__global__ __launch_bounds__(256) void k_agg(
    const _Float16* __restrict__ x16, const int* __restrict__ srcA,
    const int* __restrict__ off, const float* __restrict__ hsum,
    const float* __restrict__ rinv, float* __restrict__ agg) {
  int n = blockIdx.x * 4 + (threadIdx.x >> 6);
  if (n >= NV) return;
  int l = threadIdx.x & 63;
  float4 s = ((const float4*)(hsum + (size_t)n * D))[l];
  int o0 = off[n], o1 = off[n + 1];
  for (int j = o0; j < o1; j++) {
    int src = srcA[j];
    f16x4 v = ((const f16x4*)(x16 + (size_t)src * D))[l];
    s.x += (float)v[0]; s.y += (float)v[1];
    s.z += (float)v[2]; s.w += (float)v[3];
  }
  float r = rinv[n];
  float4 o = {s.x * r, s.y * r, s.z * r, s.w * r};
  ((float4*)(agg + (size_t)n * D))[l] = o;
}

// ---- weight prep: W[K][256] f32 -> Wf_hi/Wf_lo [K/8][256][8] bf16 ----------
__global__ __launch_bounds__(256) void k_wprep(const float* __restrict__ W,
                                               short* __restrict__ Wh,
                                               short* __restrict__ Wl) {
  __shared__ float tl[32][260];
  int tid = threadIdx.x;
  int k0 = blockIdx.x * 32;
#pragma unroll
  for (int i = 0; i < 32; i++) tl[i][tid] = W[(size_t)(k0 + i) * 256 + tid];
  __syncthreads();
  bf16x8* WhV = (bf16x8*)Wh;
  bf16x8* WlV = (bf16x8*)Wl;
#pragma unroll
  for (int kg = 0; kg < 4; kg++) {
    bf16x8 ph, pl;
#pragma unroll
    for (int j = 0; j < 8; j++) {
      short h, lo;
      split2(tl[kg * 8 + j][tid], h, lo);
      ph[j] = h; pl[j] = lo;
    }
    WhV[(size_t)((k0 >> 3) + kg) * 256 + tid] = ph;
    WlV[(size_t)((k0 >> 3) + kg) * 256 + tid] = pl;
  }
}

// ---- qW[n] = q @ pred_W1[:256,n] + pred_b1[n] ------------------------------
__global__ void k_qw(const float* __restrict__ q, const float* __restrict__ W1,
                     const float* __restrict__ b1, float* __restrict__ qW) {
  __shared__ float ql[D];
  int n = threadIdx.x;
  ql[n] = q[n];
  __syncthreads();
  float s = b1[n];
  for (int k = 0; k < D; k++) s += ql[k] * W1[(size_t)k * D + n];
  qW[n] = s;
}

// ---- generic MFMA GEMM: out = epi(A[M x K] @ Wf + ...), N=256 --------------
enum AM { A_SINGLE, A_DUAL };
enum EP { EP_RELU_BIAS, EP_RELU_F16, EP_PLAIN_F16, EP_ADDC, EP_EDGE };

template<int AMODE>
__device__ inline void loadA8(const float* __restrict__ A0, const float* __restrict__ A1,
                              int M, int row, int k, float* v) {
  if (row >= M) {
#pragma unroll
    for (int j = 0; j < 8; j++) v[j] = 0.f;
    return;
  }
  const float* src = (AMODE == A_SINGLE || k < 256) ? (A0 + (size_t)row * 256 + k)
                                                    : (A1 + (size_t)row * 256 + (k - 256));
  const float4* p = (const float4*)src;
  float4 a = p[0], b = p[1];
  v[0] = a.x; v[1] = a.y; v[2] = a.z; v[3] = a.w;
  v[4] = b.x; v[5] = b.y; v[6] = b.z; v[7] = b.w;
}

template<int AMODE, int EPI>
__global__ __launch_bounds__(256) void k_gemm(
    const float* __restrict__ A0, const float* __restrict__ A1,
    const float* __restrict__ addm, const float* __restrict__ rv,
    const short* __restrict__ Wh, const short* __restrict__ Wl,
    const float* __restrict__ bias, float* __restrict__ out,
    _Float16* __restrict__ out16,
    const int* __restrict__ eidx,
    const _Float16* __restrict__ HEh16, const _Float16* __restrict__ HEt16,
    const float* __restrict__ qW, const float* __restrict__ pW2,
    const float* __restrict__ pb2, const float* __restrict__ noise,
    int M, int K) {
  // staging (16 KB) overlaid with EP_EDGE's EA2 tile (32 KB)
  __shared__ short smemS[(EPI == EP_EDGE) ? 16384 : 8192];
  __shared__ int ehS[64], etS[64];

  const int tid = threadIdx.x;
  const int w = tid >> 6;
  const int lane31 = tid & 31;
  const int hw = (tid >> 5) & 1;
  const int m0 = blockIdx.x * 64;

  if (EPI == EP_EDGE) {
    if (tid < 64) { ehS[tid] = eidx[m0 + tid]; etS[tid] = eidx[E + m0 + tid]; }
  }

  f32x16 acc[2][2];
#pragma unroll
  for (int a = 0; a < 2; a++)
#pragma unroll
    for (int b = 0; b < 2; b++)
#pragma unroll
      for (int i = 0; i < 16; i++) acc[a][b][i] = 0.f;

  const int col0 = (w << 6) + lane31;
  const int col1 = col0 + 32;
  const bf16x8* WhV = (const bf16x8*)Wh;
  const bf16x8* WlV = (const bf16x8*)Wl;
  bf16x8* AhV = (bf16x8*)smemS;
  bf16x8* AlV = (bf16x8*)(smemS + 4096);
  const int srow = tid >> 3;
  const int skg = tid & 7;

  for (int k0 = 0; k0 < K; k0 += 64) {
    __syncthreads();
    {
      float v[8];
      bf16x8 ph, pl;
      loadA8<AMODE>(A0, A1, M, m0 + srow, k0 + skg * 8, v);
#pragma unroll
      for (int j = 0; j < 8; j++) { short h, lo; split2(v[j], h, lo); ph[j] = h; pl[j] = lo; }
      AhV[skg * 64 + srow] = ph;
      AlV[skg * 64 + srow] = pl;
      loadA8<AMODE>(A0, A1, M, m0 + srow + 32, k0 + skg * 8, v);
#pragma unroll
      for (int j = 0; j < 8; j++) { short h, lo; split2(v[j], h, lo); ph[j] = h; pl[j] = lo; }
      AhV[skg * 64 + srow + 32] = ph;
      AlV[skg * 64 + srow + 32] = pl;
    }
    __syncthreads();
#pragma unroll
    for (int ks = 0; ks < 4; ks++) {
      const int kgl = 2 * ks + hw;
      bf16x8 a0h = AhV[kgl * 64 + lane31];
      bf16x8 a0l = AlV[kgl * 64 + lane31];
      bf16x8 a1h = AhV[kgl * 64 + 32 + lane31];
      bf16x8 a1l = AlV[kgl * 64 + 32 + lane31];
      size_t wi = (size_t)((k0 >> 3) + kgl) * 256;
      bf16x8 b0h = WhV[wi + col0], b0l = WlV[wi + col0];
      bf16x8 b1h = WhV[wi + col1], b1l = WlV[wi + col1];
      acc[0][0] = MFMA(a0h, b0h, acc[0][0]);
      acc[0][0] = MFMA(a0l, b0h, acc[0][0]);
      acc[0][0] = MFMA(a0h, b0l, acc[0][0]);
      acc[0][1] = MFMA(a0h, b1h, acc[0][1]);
      acc[0][1] = MFMA(a0l, b1h, acc[0][1]);
      acc[0][1] = MFMA(a0h, b1l, acc[0][1]);
      acc[1][0] = MFMA(a1h, b0h, acc[1][0]);
      acc[1][0] = MFMA(a1l, b0h, acc[1][0]);
      acc[1][0] = MFMA(a1h, b0l, acc[1][0]);
      acc[1][1] = MFMA(a1h, b1h, acc[1][1]);
      acc[1][1] = MFMA(a1l, b1h, acc[1][1]);
      acc[1][1] = MFMA(a1h, b1l, acc[1][1]);
    }
  }

  if (EPI == EP_RELU_BIAS) {
    float b0v = bias[col0], b1v = bias[col1];
#pragma unroll
    for (int rf = 0; rf < 2; rf++)
#pragma unroll
      for (int g = 0; g < 4; g++)
#pragma unroll
        for (int q = 0; q < 4; q++) {
          int row = m0 + 32 * rf + q + 8 * g + 4 * hw;
          if (row < M) {
            float v0 = fmaxf(acc[rf][0][4 * g + q] + b0v, 0.f);
            float v1 = fmaxf(acc[rf][1][4 * g + q] + b1v, 0.f);
            out[(size_t)row * 256 + col0] = v0;
            out[(size_t)row * 256 + col1] = v1;
            if (out16) {
              out16[(size_t)row * 256 + col0] = (_Float16)v0;
              out16[(size_t)row * 256 + col1] = (_Float16)v1;
            }
          }
        }
  }
  if (EPI == EP_RELU_F16) {
    float b0v = bias[col0], b1v = bias[col1];
#pragma unroll
    for (int rf = 0; rf < 2; rf++)
#pragma unroll
      for (int g = 0; g < 4; g++)
#pragma unroll
        for (int q = 0; q < 4; q++) {
          int row = m0 + 32 * rf + q + 8 * g + 4 * hw;
          if (row < M) {
            out16[(size_t)row * 256 + col0] =
                (_Float16)fmaxf(acc[rf][0][4 * g + q] + b0v, 0.f);
            out16[(size_t)row * 256 + col1] =
                (_Float16)fmaxf(acc[rf][1][4 * g + q] + b1v, 0.f);
          }
        }
  }
  if (EPI == EP_PLAIN_F16) {
#pragma unroll
    for (int rf = 0; rf < 2; rf++)
#pragma unroll
      for (int g = 0; g < 4; g++)
#pragma unroll
        for (int q = 0; q < 4; q++) {
          int row = m0 + 32 * rf + q + 8 * g + 4 * hw;
          if (row < M) {
            out16[(size_t)row * 256 + col0] = (_Float16)acc[rf][0][4 * g + q];
            out16[(size_t)row * 256 + col1] = (_Float16)acc[rf][1][4 * g + q];
          }
        }
  }
  if (EPI == EP_ADDC) {
    float b0v = bias[col0], b1v = bias[col1];
#pragma unroll
    for (int rf = 0; rf < 2; rf++)
#pragma unroll
      for (int g = 0; g < 4; g++)
#pragma unroll
        for (int q = 0; q < 4; q++) {
          int row = m0 + 32 * rf + q + 8 * g + 4 * hw;
          if (row < M) {
            float dr = rv[row];
            out[(size_t)row * 256 + col0] =
                acc[rf][0][4 * g + q] + addm[(size_t)row * 256 + col0] + dr * b0v;
            out[(size_t)row * 256 + col1] =
                acc[rf][1][4 * g + q] + addm[(size_t)row * 256 + col1] + dr * b1v;
          }
        }
  }
  if (EPI == EP_EDGE) {
    // fold qW, stage EA2 tile to LDS as f16 (overlaid on staging buffer)
    float qw0 = qW[col0], qw1 = qW[col1];
    _Float16* eLDS = (_Float16*)smemS;
    __syncthreads();   // staging LDS fully consumed by all waves
#pragma unroll
    for (int rf = 0; rf < 2; rf++)
#pragma unroll
      for (int g = 0; g < 4; g++)
#pragma unroll
        for (int q = 0; q < 4; q++) {
          int rl = 32 * rf + q + 8 * g + 4 * hw;
          eLDS[rl * 256 + col0] = (_Float16)(acc[rf][0][4 * g + q] + qw0);
          eLDS[rl * 256 + col1] = (_Float16)(acc[rf][1][4 * g + q] + qw1);
        }
    __syncthreads();
    const int l64 = tid & 63;
    float4 w24 = ((const float4*)pW2)[l64];
    float b2v = pb2[0];
    const f16x4* eV = (const f16x4*)eLDS;
#pragma unroll
    for (int i = 0; i < 16; i++) {
      int el = w * 16 + i;
      int hh = ehS[el], tt = etS[el];
      f16x4 a = eV[el * 64 + l64];
      f16x4 hN = ((const f16x4*)(HEh16 + (size_t)hh * 256))[l64];
      f16x4 tN = ((const f16x4*)(HEt16 + (size_t)tt * 256))[l64];
      float s = fmaxf((float)a[0] + (float)hN[0] + (float)tN[0], 0.f) * w24.x
              + fmaxf((float)a[1] + (float)hN[1] + (float)tN[1], 0.f) * w24.y
              + fmaxf((float)a[2] + (float)hN[2] + (float)tN[2], 0.f) * w24.z
              + fmaxf((float)a[3] + (float)hN[3] + (float)tN[3], 0.f) * w24.w;
#pragma unroll
      for (int m = 1; m <= 32; m <<= 1) s += __shfl_xor(s, m);
      if (l64 == 0) {
        int e = m0 + el;
        float lg = s + b2v;
        float nz = noise[e];
        float rn = logf(nz) - logf(1.f - nz);
        out[e] = lg;
        out[E + e] = 1.f / (1.f + expf(-(lg + rn)));
      }
    }
  }
}

extern "C" void kernel_launch(void* const* d_in, const int* in_sizes, int n_in,
                              void* d_out, int out_size, void* d_ws, size_t ws_size,
                              hipStream_t stream) {
  const float* entity = (const float*)d_in[0];
  const float* ea     = (const float*)d_in[1];
  const float* q      = (const float*)d_in[2];
  const float* noise  = (const float*)d_in[3];
  const float* W_pr1  = (const float*)d_in[4];
  const float* b_pr1  = (const float*)d_in[5];
  const float* W_pr2  = (const float*)d_in[6];
  const float* b_pr2  = (const float*)d_in[7];
  const float* sW0    = (const float*)d_in[8];
  const float* sb0    = (const float*)d_in[9];
  const float* sW1    = (const float*)d_in[10];
  const float* sb1    = (const float*)d_in[11];
  const float* pW1    = (const float*)d_in[12];
  const float* pb1    = (const float*)d_in[13];
  const float* pW2    = (const float*)d_in[14];
  const float* pb2    = (const float*)d_in[15];
  const void*  ei_raw = d_in[16];

  char* ws = (char*)d_ws;
  const size_t NDB  = (size_t)NV * D * 4;   // 51.2 MB (f32 node matrix)
  const size_t NDH  = (size_t)NV * D * 2;   // 25.6 MB (f16 node matrix)
  const size_t EDH  = (size_t)E * D * 2;    // 102.4 MB (f16 edge matrix)
  size_t off_b = 0;
  char* tmpR    = ws + off_b; off_b += EDH;        // tmp16 -> out0|out1 (f32)
  float* hsum   = (float*)(ws + off_b); off_b += NDB;
  char* hidR    = ws + off_b; off_b += NDB;        // hidsum -> agg -> HEh16|HEt16
  char* entR    = ws + off_b; off_b += NDH;        // entity16 -> out016
  auto alloc_w = [&](int K) { short* p = (short*)(ws + off_b); off_b += (size_t)K * 512; return p; };
  short* Wpr1h = alloc_w(256); short* Wpr1l = alloc_w(256);
  short* Wpr2h = alloc_w(256); short* Wpr2l = alloc_w(256);
  short* sW0h  = alloc_w(512); short* sW0l  = alloc_w(512);
  short* sW1h  = alloc_w(512); short* sW1l  = alloc_w(512);
  short* Whehh = alloc_w(512); short* Whehl = alloc_w(512);
  short* Weah  = alloc_w(256); short* Weal  = alloc_w(256);
  short* Wheth = alloc_w(512); short* Whetl = alloc_w(512);
  float* rinv   = (float*)(ws + off_b); off_b += (size_t)NV * 4;
  float* degrev = (float*)(ws + off_b); off_b += (size_t)NV * 4;
  float* qW     = (float*)(ws + off_b); off_b += 1024;
  int*   ei32   = (int*)(ws + off_b);   off_b += (size_t)TWOE * 4;
  int*   eidA   = (int*)(ws + off_b);   off_b += (size_t)TWOE * 4;
  int*   srcA   = (int*)(ws + off_b);   off_b += (size_t)TWOE * 4;
  int*   offA   = (int*)(ws + off_b);   off_b += (size_t)(NV + 1) * 4;
  int*   deg    = (int*)(ws + off_b);   off_b += (size_t)NV * 4;
  int*   cursor = (int*)(ws + off_b);   off_b += (size_t)NV * 4;
  int*   flag   = (int*)(ws + off_b);   off_b += 64;

  // lifetime aliases
  _Float16* tmp16    = (_Float16*)tmpR;       // live G1 -> k_gath_h
  float*    out0     = (float*)tmpR;          // live sage0 -> HE GEMMs
  float*    out1     = (float*)(tmpR + NDB);  // live sage1 -> HE GEMMs
  float*    hidsum   = (float*)hidR;          // live gath -> ADDC
  float*    agg      = (float*)hidR;          // live agg -> sage GEMM (per layer)
  _Float16* HEh16    = (_Float16*)hidR;       // live HE-GEMM -> EP_EDGE
  _Float16* HEt16    = (_Float16*)(hidR + NDH);
  _Float16* entity16 = (_Float16*)entR;       // live conv -> agg0
  _Float16* out016   = (_Float16*)entR;       // live sage0 -> agg1

  // ---- indices & CSR ----
  k_detect<<<1, 256, 0, stream>>>(ei_raw, flag);
  k_convert<<<(TWOE + 255) / 256, 256, 0, stream>>>(ei_raw, flag, ei32);
  hipMemsetAsync(deg, 0, (size_t)NV * 4, stream);
  hipMemsetAsync(cursor, 0, (size_t)NV * 4, stream);
  k_deg<<<(TWOE + 255) / 256, 256, 0, stream>>>(ei32, deg);
  k_scan<<<1, 1024, 0, stream>>>(deg, offA);
  k_fill<<<(TWOE + 255) / 256, 256, 0, stream>>>(ei32, offA, cursor, eidA, srcA);
  k_rinv<<<(NV + 255) / 256, 256, 0, stream>>>(offA, rinv);

  // ---- weight prep + entity f16 shadow ----
  k_wprep<<<256 / 32, 256, 0, stream>>>(W_pr1, Wpr1h, Wpr1l);
  k_wprep<<<256 / 32, 256, 0, stream>>>(W_pr2, Wpr2h, Wpr2l);
  k_wprep<<<512 / 32, 256, 0, stream>>>(sW0, sW0h, sW0l);
  k_wprep<<<512 / 32, 256, 0, stream>>>(sW1, sW1h, sW1l);
  k_wprep<<<512 / 32, 256, 0, stream>>>(pW1 + 256 * 256, Whehh, Whehl);
  k_wprep<<<256 / 32, 256, 0, stream>>>(pW1 + 768 * 256, Weah, Weal);
  k_wprep<<<512 / 32, 256, 0, stream>>>(pW1 + 1024 * 256, Wheth, Whetl);
  k_conv16<<<(NV * D / 8 + 255) / 256, 256, 0, stream>>>(entity, entity16, NV * D / 8);

  // ---- proj: tmp16 = relu(ea @ Wpr1 + b_pr1)  [f16] ----
  k_gemm<A_SINGLE, EP_RELU_F16><<<E / 64, 256, 0, stream>>>(
      ea, nullptr, nullptr, nullptr, Wpr1h, Wpr1l, b_pr1, nullptr, tmp16,
      nullptr, nullptr, nullptr, nullptr, nullptr, nullptr, nullptr, E, 256);
  // gather: hsum = sum_fwd ea; hidsum = sum_rev hid; degrev
  k_gath_h<<<(NV + 3) / 4, 256, 0, stream>>>(ea, tmp16, eidA, offA, hsum, hidsum, degrev);
  // hsum += hidsum @ Wpr2 + degrev*b_pr2   (in-place)
  k_gemm<A_SINGLE, EP_ADDC><<<(NV + 63) / 64, 256, 0, stream>>>(
      hidsum, nullptr, hsum, degrev, Wpr2h, Wpr2l, b_pr2, hsum, nullptr,
      nullptr, nullptr, nullptr, nullptr, nullptr, nullptr, nullptr, NV, 256);

  // ---- layer 0 ----
  k_agg<<<(NV + 3) / 4, 256, 0, stream>>>(entity16, srcA, offA, hsum, rinv, agg);
  k_gemm<A_DUAL, EP_RELU_BIAS><<<(NV + 63) / 64, 256, 0, stream>>>(
      entity, agg, nullptr, nullptr, sW0h, sW0l, sb0, out0, out016,
      nullptr, nullptr, nullptr, nullptr, nullptr, nullptr, nullptr, NV, 512);
  // ---- layer 1 ----
  k_agg<<<(NV + 3) / 4, 256, 0, stream>>>(out016, srcA, offA, hsum, rinv, agg);
  k_gemm<A_DUAL, EP_RELU_BIAS><<<(NV + 63) / 64, 256, 0, stream>>>(
      out0, agg, nullptr, nullptr, sW1h, sW1l, sb1, out1, nullptr,
      nullptr, nullptr, nullptr, nullptr, nullptr, nullptr, nullptr, NV, 512);

  // ---- pred node-side GEMMs (f16 outputs, overlay on agg region) ----
  k_gemm<A_DUAL, EP_PLAIN_F16><<<(NV + 63) / 64, 256, 0, stream>>>(
      out0, out1, nullptr, nullptr, Whehh, Whehl, nullptr, nullptr, HEh16,
      nullptr, nullptr, nullptr, nullptr, nullptr, nullptr, nullptr, NV, 512);
  k_gemm<A_DUAL, EP_PLAIN_F16><<<(NV + 63) / 64, 256, 0, stream>>>(
      out0, out1, nullptr, nullptr, Wheth, Whetl, nullptr, nullptr, HEt16,
      nullptr, nullptr, nullptr, nullptr, nullptr, nullptr, nullptr, NV, 512);

  k_qw<<<1, 256, 0, stream>>>(q, pW1, pb1, qW);

  // ---- fused: EA2 GEMM + per-edge combine + w2-dot + sampling ----
  k_gemm<A_SINGLE, EP_EDGE><<<E / 64, 256, 0, stream>>>(
      ea, nullptr, nullptr, nullptr, Weah, Weal, nullptr, (float*)d_out, nullptr,
      ei32, HEh16, HEt16, qW, pW2, pb2, noise, E, 256);
}

// Round 5
// 871.943 us; speedup vs baseline: 8.1703x; 1.2247x over previous
//
#include <hip/hip_runtime.h>
#include <math.h>

// FineGrainedRetriever round 5: all-f16 single-MFMA GEMMs (mfma_f32_32x32x16_f16,
// 1 mfma/tile), conflict-free lane-contiguous LDS staging, EA2 GEMM de-fused from
// edge combine (lean k_edge kernel), HEh+HEt fused into one dual-weight GEMM,
// f16-only activations. CSR gathers unchanged.

namespace {
constexpr int E    = 200000;
constexpr int NV   = 50000;
constexpr int D    = 256;
constexpr int TWOE = 2 * E;
}

typedef __attribute__((ext_vector_type(8))) _Float16 f16x8;
typedef __attribute__((ext_vector_type(4))) _Float16 f16x4;
typedef __attribute__((ext_vector_type(16))) float f32x16;

#define MFMA16(a, b, c) __builtin_amdgcn_mfma_f32_32x32x16_f16((a), (b), (c), 0, 0, 0)

// ---- edge_index dtype probe (int64 vs int32) -------------------------------
__global__ void k_detect(const void* ei_raw, int* flag) {
  __shared__ int bad;
  if (threadIdx.x == 0) bad = 0;
  __syncthreads();
  const long long* p = (const long long*)ei_raw;
  long long v = p[threadIdx.x];
  if (v < 0 || v >= (long long)NV) atomicOr(&bad, 1);
  __syncthreads();
  if (threadIdx.x == 0) *flag = bad ? 0 : 1;  // 1 => int64
}

__global__ void k_convert(const void* ei_raw, const int* __restrict__ flag,
                          int* __restrict__ ei32) {
  int i = blockIdx.x * 256 + threadIdx.x;
  if (i >= TWOE) return;
  if (*flag) ei32[i] = (int)((const long long*)ei_raw)[i];
  else       ei32[i] = ((const int*)ei_raw)[i];
}

// ---- CSR build -------------------------------------------------------------
__global__ void k_deg(const int* __restrict__ ei32, int* __restrict__ deg) {
  int de = blockIdx.x * 256 + threadIdx.x;
  if (de >= TWOE) return;
  int dst = (de < E) ? ei32[E + de] : ei32[de - E];
  atomicAdd(&deg[dst], 1);
}

__global__ __launch_bounds__(1024) void k_scan(const int* __restrict__ deg,
                                               int* __restrict__ off) {
  __shared__ int wsum[16];
  __shared__ int carryS;
  int tid = threadIdx.x;
  int lane = tid & 63, wv = tid >> 6;
  if (tid == 0) carryS = 0;
  __syncthreads();
  for (int base = 0; base < NV; base += 1024) {
    int i = base + tid;
    int v = (i < NV) ? deg[i] : 0;
    int s = v;
#pragma unroll
    for (int d = 1; d < 64; d <<= 1) {
      int t = __shfl_up(s, d);
      if (lane >= d) s += t;
    }
    if (lane == 63) wsum[wv] = s;
    int carry = carryS;
    __syncthreads();
    if (wv == 0) {
      int ws = (lane < 16) ? wsum[lane] : 0;
#pragma unroll
      for (int d = 1; d < 16; d <<= 1) {
        int t = __shfl_up(ws, d);
        if (lane >= d) ws += t;
      }
      if (lane < 16) wsum[lane] = ws;
    }
    __syncthreads();
    int wexcl = (wv == 0) ? 0 : wsum[wv - 1];
    if (i < NV) off[i] = carry + wexcl + s - v;
    if (tid == 1023) carryS = carry + wsum[15];
    __syncthreads();
  }
  if (tid == 0) off[NV] = carryS;
}

__global__ void k_fill(const int* __restrict__ ei32, const int* __restrict__ off,
                       int* __restrict__ cursor, int* __restrict__ eidA,
                       int* __restrict__ srcA) {
  int de = blockIdx.x * 256 + threadIdx.x;
  if (de >= TWOE) return;
  int dst = (de < E) ? ei32[E + de] : ei32[de - E];
  int p = atomicAdd(&cursor[dst], 1);
  int idx = off[dst] + p;
  eidA[idx] = de;
  srcA[idx] = ei32[de];
}

__global__ void k_rinv(const int* __restrict__ off, float* __restrict__ rinv) {
  int n = blockIdx.x * 256 + threadIdx.x;
  if (n < NV) {
    int d = off[n + 1] - off[n];
    rinv[n] = 1.f / fmaxf((float)d, 1.f);
  }
}

// ---- f32 -> f16 copy (8 elems/thread) --------------------------------------
__global__ void k_conv16(const float* __restrict__ x, _Float16* __restrict__ y,
                         int n8) {
  int i = blockIdx.x * 256 + threadIdx.x;
  if (i >= n8) return;
  const float4* p = (const float4*)x;
  float4 a = p[2 * i], b = p[2 * i + 1];
  f16x8 o;
  o[0] = (_Float16)a.x; o[1] = (_Float16)a.y; o[2] = (_Float16)a.z; o[3] = (_Float16)a.w;
  o[4] = (_Float16)b.x; o[5] = (_Float16)b.y; o[6] = (_Float16)b.z; o[7] = (_Float16)b.w;
  ((f16x8*)y)[i] = o;
}

// ---- gather: hsum[n] = sum fwd ea rows (f32); hid16 = sum rev hid; degrev --
__global__ __launch_bounds__(256) void k_gath_h(
    const float* __restrict__ ea, const _Float16* __restrict__ tmp16,
    const int* __restrict__ eidA, const int* __restrict__ off,
    float* __restrict__ hsum, _Float16* __restrict__ hid16,
    float* __restrict__ degrev) {
  int n = blockIdx.x * 4 + (threadIdx.x >> 6);
  if (n >= NV) return;
  int l = threadIdx.x & 63;
  float4 fs = {0.f, 0.f, 0.f, 0.f}, hv = {0.f, 0.f, 0.f, 0.f};
  int o0 = off[n], o1 = off[n + 1];
  int dr = 0;
  for (int j = o0; j < o1; j++) {
    int de = eidA[j];
    if (de < E) {
      float4 v = ((const float4*)(ea + (size_t)de * D))[l];
      fs.x += v.x; fs.y += v.y; fs.z += v.z; fs.w += v.w;
    } else {
      f16x4 v = ((const f16x4*)(tmp16 + (size_t)(de - E) * D))[l];
      hv.x += (float)v[0]; hv.y += (float)v[1];
      hv.z += (float)v[2]; hv.w += (float)v[3];
      dr++;
    }
  }
  ((float4*)(hsum + (size_t)n * D))[l] = fs;
  f16x4 ho;
  ho[0] = (_Float16)hv.x; ho[1] = (_Float16)hv.y;
  ho[2] = (_Float16)hv.z; ho[3] = (_Float16)hv.w;
  ((f16x4*)(hid16 + (size_t)n * D))[l] = ho;
  if (l == 0) degrev[n] = (float)dr;
}

// ---- per-layer aggregate: agg16[n] = (sum_j x16[src_j] + hsum[n])*rinv[n] --
__global__ __launch_bounds__(256) void k_agg(
    const _Float16* __restrict__ x16, const int* __restrict__ srcA,
    const int* __restrict__ off, const float* __restrict__ hsum,
    const float* __restrict__ rinv, _Float16* __restrict__ agg16) {
  int n = blockIdx.x * 4 + (threadIdx.x >> 6);
  if (n >= NV) return;
  int l = threadIdx.x & 63;
  float4 s = ((const float4*)(hsum + (size_t)n * D))[l];
  int o0 = off[n], o1 = off[n + 1];
  for (int j = o0; j < o1; j++) {
    int src = srcA[j];
    f16x4 v = ((const f16x4*)(x16 + (size_t)src * D))[l];
    s.x += (float)v[0]; s.y += (float)v[1];
    s.z += (float)v[2]; s.w += (float)v[3];
  }
  float r = rinv[n];
  f16x4 o;
  o[0] = (_Float16)(s.x * r); o[1] = (_Float16)(s.y * r);
  o[2] = (_Float16)(s.z * r); o[3] = (_Float16)(s.w * r);
  ((f16x4*)(agg16 + (size_t)n * D))[l] = o;
}

// ---- weight prep: W[K][256] f32 -> Wf [K/8][256][8] f16 --------------------
__global__ __launch_bounds__(256) void k_wprep(const float* __restrict__ W,
                                               _Float16* __restrict__ Wf) {
  __shared__ float tl[32][260];
  int tid = threadIdx.x;
  int k0 = blockIdx.x * 32;
#pragma unroll
  for (int i = 0; i < 32; i++) tl[i][tid] = W[(size_t)(k0 + i) * 256 + tid];
  __syncthreads();
  f16x8* WfV = (f16x8*)Wf;
#pragma unroll
  for (int kg = 0; kg < 4; kg++) {
    f16x8 p;
#pragma unroll
    for (int j = 0; j < 8; j++) p[j] = (_Float16)tl[kg * 8 + j][tid];
    WfV[(size_t)((k0 >> 3) + kg) * 256 + tid] = p;
  }
}

// ---- qW[n] = q @ pred_W1[:256,n] + pred_b1[n] ------------------------------
__global__ void k_qw(const float* __restrict__ q, const float* __restrict__ W1,
                     const float* __restrict__ b1, float* __restrict__ qW) {
  __shared__ float ql[D];
  int n = threadIdx.x;
  ql[n] = q[n];
  __syncthreads();
  float s = b1[n];
  for (int k = 0; k < D; k++) s += ql[k] * W1[(size_t)k * D + n];
  qW[n] = s;
}

// ---- generic f16 MFMA GEMM: out = epi(A[M x K] @ Wf), N=256 per weight -----
enum AM { AF32, AF16, AF16D };
enum EP { EP_RELU16, EP_Q16, EP_ADDC, EP_HE2 };

template<int AMODE, int EPI>
__global__ __launch_bounds__(256) void k_gemm(
    const void* Av0, const void* Av1,
    const float* __restrict__ addm, const float* __restrict__ rv,
    const _Float16* __restrict__ Wf, const _Float16* __restrict__ Wf2,
    const float* __restrict__ bias, const float* __restrict__ qW,
    float* __restrict__ outf, _Float16* __restrict__ o16a,
    _Float16* __restrict__ o16b, int M, int K) {
  __shared__ _Float16 AS[8 * 64 * 8];   // 8 KB: [kg][row][8]
  const int tid = threadIdx.x;
  const int w = tid >> 6;
  const int lane31 = tid & 31;
  const int hw = (tid >> 5) & 1;
  const int m0 = blockIdx.x * 64;
  const int col0 = (w << 6) + lane31;   // 0..255
  const int col1 = col0 + 32;

  f32x16 acc[2][2], acc2[2][2];
#pragma unroll
  for (int a = 0; a < 2; a++)
#pragma unroll
    for (int b = 0; b < 2; b++)
#pragma unroll
      for (int i = 0; i < 16; i++) { acc[a][b][i] = 0.f; acc2[a][b][i] = 0.f; }

  f16x8* ASV = (f16x8*)AS;
  const f16x8* WV  = (const f16x8*)Wf;
  const f16x8* WV2 = (const f16x8*)Wf2;
  const int srow = tid & 31;            // lane-contiguous LDS writes
  const int skg  = tid >> 5;            // 0..7

  for (int k0 = 0; k0 < K; k0 += 64) {
    __syncthreads();
#pragma unroll
    for (int rr = 0; rr < 2; rr++) {
      int row = srow + 32 * rr;
      int k = k0 + skg * 8;
      f16x8 p;
      if (AMODE == AF32) {
        const float* src = (const float*)Av0 + (size_t)(m0 + row) * 256 + k;
        float4 a = ((const float4*)src)[0], b = ((const float4*)src)[1];
        p[0] = (_Float16)a.x; p[1] = (_Float16)a.y;
        p[2] = (_Float16)a.z; p[3] = (_Float16)a.w;
        p[4] = (_Float16)b.x; p[5] = (_Float16)b.y;
        p[6] = (_Float16)b.z; p[7] = (_Float16)b.w;
      } else {
        const _Float16* base =
            (AMODE == AF16D && k >= 256)
                ? ((const _Float16*)Av1 + (size_t)(m0 + row) * 256 + (k - 256))
                : ((const _Float16*)Av0 + (size_t)(m0 + row) * 256 + k);
        p = *(const f16x8*)base;
      }
      ASV[skg * 64 + row] = p;
    }
    __syncthreads();
#pragma unroll
    for (int ks = 0; ks < 4; ks++) {
      const int kgl = 2 * ks + hw;
      f16x8 a0 = ASV[kgl * 64 + lane31];
      f16x8 a1 = ASV[kgl * 64 + 32 + lane31];
      size_t wi = (size_t)((k0 >> 3) + kgl) * 256;
      f16x8 b0 = WV[wi + col0];
      f16x8 b1 = WV[wi + col1];
      acc[0][0] = MFMA16(a0, b0, acc[0][0]);
      acc[0][1] = MFMA16(a0, b1, acc[0][1]);
      acc[1][0] = MFMA16(a1, b0, acc[1][0]);
      acc[1][1] = MFMA16(a1, b1, acc[1][1]);
      if (EPI == EP_HE2) {
        f16x8 c0 = WV2[wi + col0];
        f16x8 c1 = WV2[wi + col1];
        acc2[0][0] = MFMA16(a0, c0, acc2[0][0]);
        acc2[0][1] = MFMA16(a0, c1, acc2[0][1]);
        acc2[1][0] = MFMA16(a1, c0, acc2[1][0]);
        acc2[1][1] = MFMA16(a1, c1, acc2[1][1]);
      }
    }
  }

  if (EPI == EP_RELU16) {
    float b0v = bias[col0], b1v = bias[col1];
#pragma unroll
    for (int rf = 0; rf < 2; rf++)
#pragma unroll
      for (int g = 0; g < 4; g++)
#pragma unroll
        for (int qq = 0; qq < 4; qq++) {
          int row = m0 + 32 * rf + qq + 8 * g + 4 * hw;
          if (row < M) {
            o16a[(size_t)row * 256 + col0] =
                (_Float16)fmaxf(acc[rf][0][4 * g + qq] + b0v, 0.f);
            o16a[(size_t)row * 256 + col1] =
                (_Float16)fmaxf(acc[rf][1][4 * g + qq] + b1v, 0.f);
          }
        }
  }
  if (EPI == EP_Q16) {
    float q0 = qW[col0], q1 = qW[col1];
#pragma unroll
    for (int rf = 0; rf < 2; rf++)
#pragma unroll
      for (int g = 0; g < 4; g++)
#pragma unroll
        for (int qq = 0; qq < 4; qq++) {
          int row = m0 + 32 * rf + qq + 8 * g + 4 * hw;
          if (row < M) {
            o16a[(size_t)row * 256 + col0] = (_Float16)(acc[rf][0][4 * g + qq] + q0);
            o16a[(size_t)row * 256 + col1] = (_Float16)(acc[rf][1][4 * g + qq] + q1);
          }
        }
  }
  if (EPI == EP_ADDC) {
    float b0v = bias[col0], b1v = bias[col1];
#pragma unroll
    for (int rf = 0; rf < 2; rf++)
#pragma unroll
      for (int g = 0; g < 4; g++)
#pragma unroll
        for (int qq = 0; qq < 4; qq++) {
          int row = m0 + 32 * rf + qq + 8 * g + 4 * hw;
          if (row < M) {
            float dr = rv[row];
            outf[(size_t)row * 256 + col0] =
                acc[rf][0][4 * g + qq] + addm[(size_t)row * 256 + col0] + dr * b0v;
            outf[(size_t)row * 256 + col1] =
                acc[rf][1][4 * g + qq] + addm[(size_t)row * 256 + col1] + dr * b1v;
          }
        }
  }
  if (EPI == EP_HE2) {
#pragma unroll
    for (int rf = 0; rf < 2; rf++)
#pragma unroll
      for (int g = 0; g < 4; g++)
#pragma unroll
        for (int qq = 0; qq < 4; qq++) {
          int row = m0 + 32 * rf + qq + 8 * g + 4 * hw;
          if (row < M) {
            o16a[(size_t)row * 256 + col0] = (_Float16)acc[rf][0][4 * g + qq];
            o16a[(size_t)row * 256 + col1] = (_Float16)acc[rf][1][4 * g + qq];
            o16b[(size_t)row * 256 + col0] = (_Float16)acc2[rf][0][4 * g + qq];
            o16b[(size_t)row * 256 + col1] = (_Float16)acc2[rf][1][4 * g + qq];
          }
        }
  }
}

// ---- lean edge combine: logits/sampled from ea2q16 + HEh/HEt gathers -------
__global__ __launch_bounds__(256) void k_edge(
    const _Float16* __restrict__ ea2q, const _Float16* __restrict__ HEh,
    const _Float16* __restrict__ HEt, const int* __restrict__ ei32,
    const float* __restrict__ pW2, const float* __restrict__ pb2,
    const float* __restrict__ noise, float* __restrict__ dout) {
  int e = blockIdx.x * 4 + (threadIdx.x >> 6);
  int l = threadIdx.x & 63;
  int h = ei32[e], t = ei32[E + e];
  f16x4 a  = ((const f16x4*)(ea2q + (size_t)e * 256))[l];
  f16x4 hv = ((const f16x4*)(HEh + (size_t)h * 256))[l];
  f16x4 tv = ((const f16x4*)(HEt + (size_t)t * 256))[l];
  float4 wv = ((const float4*)pW2)[l];
  float s = fmaxf((float)a[0] + (float)hv[0] + (float)tv[0], 0.f) * wv.x
          + fmaxf((float)a[1] + (float)hv[1] + (float)tv[1], 0.f) * wv.y
          + fmaxf((float)a[2] + (float)hv[2] + (float)tv[2], 0.f) * wv.z
          + fmaxf((float)a[3] + (float)hv[3] + (float)tv[3], 0.f) * wv.w;
#pragma unroll
  for (int m = 1; m <= 32; m <<= 1) s += __shfl_xor(s, m);
  if (l == 0) {
    float lg = s + pb2[0];
    float nz = noise[e];
    float rn = logf(nz) - logf(1.f - nz);
    dout[e] = lg;
    dout[E + e] = 1.f / (1.f + expf(-(lg + rn)));
  }
}

extern "C" void kernel_launch(void* const* d_in, const int* in_sizes, int n_in,
                              void* d_out, int out_size, void* d_ws, size_t ws_size,
                              hipStream_t stream) {
  const float* entity = (const float*)d_in[0];
  const float* ea     = (const float*)d_in[1];
  const float* q      = (const float*)d_in[2];
  const float* noise  = (const float*)d_in[3];
  const float* W_pr1  = (const float*)d_in[4];
  const float* b_pr1  = (const float*)d_in[5];
  const float* W_pr2  = (const float*)d_in[6];
  const float* b_pr2  = (const float*)d_in[7];
  const float* sW0    = (const float*)d_in[8];
  const float* sb0    = (const float*)d_in[9];
  const float* sW1    = (const float*)d_in[10];
  const float* sb1    = (const float*)d_in[11];
  const float* pW1    = (const float*)d_in[12];
  const float* pb1    = (const float*)d_in[13];
  const float* pW2    = (const float*)d_in[14];
  const float* pb2    = (const float*)d_in[15];
  const void*  ei_raw = d_in[16];

  char* ws = (char*)d_ws;
  const size_t EDH = (size_t)E * D * 2;    // 102.4 MB f16 edge matrix
  const size_t NDB = (size_t)NV * D * 4;   // 51.2 MB f32 node matrix
  const size_t NDH = (size_t)NV * D * 2;   // 25.6 MB f16 node matrix
  const size_t PAD = 64 * 256 * 2;         // OOB tile-read slack (32 KB)
  size_t off_b = 0;
  char* r1 = ws + off_b; off_b += EDH + PAD;        // tmp16 -> ea2q16
  char* r2 = ws + off_b; off_b += NDB + PAD;        // hsum f32 -> HEh16|HEt16
  char* r3 = ws + off_b; off_b += NDH + PAD;        // hid16 -> agg16
  char* r4 = ws + off_b; off_b += NDH + PAD;        // ent16 -> out116
  char* r5 = ws + off_b; off_b += NDH + PAD;        // out016
  auto alloc_w = [&](int K) { _Float16* p = (_Float16*)(ws + off_b);
                              off_b += (size_t)K * 256 * 2; return p; };
  _Float16* Wpr1f = alloc_w(256);
  _Float16* Wpr2f = alloc_w(256);
  _Float16* sW0f  = alloc_w(512);
  _Float16* sW1f  = alloc_w(512);
  _Float16* Whehf = alloc_w(512);
  _Float16* Whetf = alloc_w(512);
  _Float16* Weaf  = alloc_w(256);
  float* rinv   = (float*)(ws + off_b); off_b += (size_t)NV * 4;
  float* degrev = (float*)(ws + off_b); off_b += (size_t)NV * 4;
  float* qW     = (float*)(ws + off_b); off_b += 1024;
  int*   ei32   = (int*)(ws + off_b);   off_b += (size_t)TWOE * 4;
  int*   eidA   = (int*)(ws + off_b);   off_b += (size_t)TWOE * 4;
  int*   srcA   = (int*)(ws + off_b);   off_b += (size_t)TWOE * 4;
  int*   offA   = (int*)(ws + off_b);   off_b += (size_t)(NV + 1) * 4;
  int*   deg    = (int*)(ws + off_b);   off_b += (size_t)NV * 4;
  int*   cursor = (int*)(ws + off_b);   off_b += (size_t)NV * 4;
  int*   flag   = (int*)(ws + off_b);   off_b += 64;

  // lifetime aliases
  _Float16* tmp16  = (_Float16*)r1;          // G1 -> gath_h
  _Float16* ea2q16 = (_Float16*)r1;          // EA2 -> k_edge
  float*    hsum   = (float*)r2;             // gath -> ADDC -> agg0/agg1
  _Float16* HEh16  = (_Float16*)r2;          // HE -> k_edge
  _Float16* HEt16  = (_Float16*)(r2 + NDH);
  _Float16* hid16  = (_Float16*)r3;          // gath -> ADDC
  _Float16* agg16  = (_Float16*)r3;          // agg -> sage (per layer)
  _Float16* ent16  = (_Float16*)r4;          // conv -> agg0/sage0
  _Float16* out116 = (_Float16*)r4;          // sage1 -> HE
  _Float16* out016 = (_Float16*)r5;          // sage0 -> agg1/sage1/HE

  // ---- indices & CSR ----
  k_detect<<<1, 256, 0, stream>>>(ei_raw, flag);
  k_convert<<<(TWOE + 255) / 256, 256, 0, stream>>>(ei_raw, flag, ei32);
  hipMemsetAsync(deg, 0, (size_t)NV * 4, stream);
  hipMemsetAsync(cursor, 0, (size_t)NV * 4, stream);
  k_deg<<<(TWOE + 255) / 256, 256, 0, stream>>>(ei32, deg);
  k_scan<<<1, 1024, 0, stream>>>(deg, offA);
  k_fill<<<(TWOE + 255) / 256, 256, 0, stream>>>(ei32, offA, cursor, eidA, srcA);
  k_rinv<<<(NV + 255) / 256, 256, 0, stream>>>(offA, rinv);

  // ---- weight prep + shadows ----
  k_wprep<<<256 / 32, 256, 0, stream>>>(W_pr1, Wpr1f);
  k_wprep<<<256 / 32, 256, 0, stream>>>(W_pr2, Wpr2f);
  k_wprep<<<512 / 32, 256, 0, stream>>>(sW0, sW0f);
  k_wprep<<<512 / 32, 256, 0, stream>>>(sW1, sW1f);
  k_wprep<<<512 / 32, 256, 0, stream>>>(pW1 + 256 * 256, Whehf);
  k_wprep<<<512 / 32, 256, 0, stream>>>(pW1 + 1024 * 256, Whetf);
  k_wprep<<<256 / 32, 256, 0, stream>>>(pW1 + 768 * 256, Weaf);
  k_conv16<<<(NV * D / 8 + 255) / 256, 256, 0, stream>>>(entity, ent16, NV * D / 8);
  k_qw<<<1, 256, 0, stream>>>(q, pW1, pb1, qW);

  // ---- proj: tmp16 = relu(ea @ Wpr1 + b_pr1) ----
  k_gemm<AF32, EP_RELU16><<<E / 64, 256, 0, stream>>>(
      ea, nullptr, nullptr, nullptr, Wpr1f, nullptr, b_pr1, nullptr,
      nullptr, tmp16, nullptr, E, 256);
  // gather: hsum = sum_fwd ea (f32); hid16 = sum_rev tmp16; degrev
  k_gath_h<<<(NV + 3) / 4, 256, 0, stream>>>(ea, tmp16, eidA, offA, hsum, hid16, degrev);
  // hsum += hid16 @ Wpr2 + degrev*b_pr2   (in place)
  k_gemm<AF16, EP_ADDC><<<(NV + 63) / 64, 256, 0, stream>>>(
      hid16, nullptr, hsum, degrev, Wpr2f, nullptr, b_pr2, nullptr,
      hsum, nullptr, nullptr, NV, 256);

  // ---- layer 0 ----
  k_agg<<<(NV + 3) / 4, 256, 0, stream>>>(ent16, srcA, offA, hsum, rinv, agg16);
  k_gemm<AF16D, EP_RELU16><<<(NV + 63) / 64, 256, 0, stream>>>(
      ent16, agg16, nullptr, nullptr, sW0f, nullptr, sb0, nullptr,
      nullptr, out016, nullptr, NV, 512);
  // ---- layer 1 ----
  k_agg<<<(NV + 3) / 4, 256, 0, stream>>>(out016, srcA, offA, hsum, rinv, agg16);
  k_gemm<AF16D, EP_RELU16><<<(NV + 63) / 64, 256, 0, stream>>>(
      out016, agg16, nullptr, nullptr, sW1f, nullptr, sb1, nullptr,
      nullptr, out116, nullptr, NV, 512);

  // ---- HE dual-weight GEMM: HEh16/HEt16 (into hsum region; hsum dead) ----
  k_gemm<AF16D, EP_HE2><<<(NV + 63) / 64, 256, 0, stream>>>(
      out016, out116, nullptr, nullptr, Whehf, Whetf, nullptr, nullptr,
      nullptr, HEh16, HEt16, NV, 512);

  // ---- EA2 GEMM: ea2q16 = ea @ Wea + qW (into r1; tmp16 dead) ----
  k_gemm<AF32, EP_Q16><<<E / 64, 256, 0, stream>>>(
      ea, nullptr, nullptr, nullptr, Weaf, nullptr, nullptr, qW,
      nullptr, ea2q16, nullptr, E, 256);

  // ---- lean edge combine ----
  k_edge<<<E / 4, 256, 0, stream>>>(ea2q16, HEh16, HEt16, ei32, pW2, pb2, noise,
                                    (float*)d_out);
}